// Round 10
// baseline (248.660 us; speedup 1.0000x reference)
//
#include <hip/hip_runtime.h>

// Problem constants (match reference)
#define NM     4
#define NDEPTH 8
#define NL     256
#define NB     8192
#define NNODES 255            // 2^8 - 1
#define STAB_PP 21845         // sum_{d<8} 4^d
#define ZBASE  (NM*NDEPTH*NB)                 // 262144 (idx region size)
#define TOTAL_IDX (ZBASE + (size_t)NM*NDEPTH*NB*NL)  // 67371008
#define INFPACK (0x7F800000ULL << 32)
#define NROWS (NM*NDEPTH*NB)  // 262144

typedef float f32x4 __attribute__((ext_vector_type(4)));

__device__ __constant__ int c_pref[8] = {0,1,5,21,85,341,1365,5461}; // (4^d-1)/3

// ---------- helpers ----------
__device__ __forceinline__ double wred(double v) {
  v += __shfl_xor(v, 1, 64);
  v += __shfl_xor(v, 2, 64);
  v += __shfl_xor(v, 4, 64);
  v += __shfl_xor(v, 8, 64);
  v += __shfl_xor(v, 16, 64);
  v += __shfl_xor(v, 32, 64);
  return v;
}
__device__ __forceinline__ void wred2(double& a, double& b) {
  #pragma unroll
  for (int m = 1; m <= 32; m <<= 1) {
    double ta = __shfl_xor(a, m, 64);
    double tb = __shfl_xor(b, m, 64);
    a += ta; b += tb;
  }
}
// DPP row_ror move of a double (two 32-bit halves). CTRL: 0x120+n = row_ror:n
// (rotation within each 16-lane row; pure VALU, no LDS op).
template<int CTRL>
__device__ __forceinline__ double dpp_ror_d(double v) {
  union { double d; int i[2]; } u, r;
  u.d = v;
  r.i[0] = __builtin_amdgcn_update_dpp(0, u.i[0], CTRL, 0xF, 0xF, true);
  r.i[1] = __builtin_amdgcn_update_dpp(0, u.i[1], CTRL, 0xF, 0xF, true);
  return r.d;
}
// xor16 within each 32-lane half via ds_swizzle BitMode (one LDS op per 32b).
__device__ __forceinline__ double swz_xor16_d(double v) {
  union { double d; int i[2]; } u, r;
  u.d = v;
  r.i[0] = __builtin_amdgcn_ds_swizzle(u.i[0], 0x401F);
  r.i[1] = __builtin_amdgcn_ds_swizzle(u.i[1], 0x401F);
  return r.d;
}
// width-32 dual sum reduction: rotation tree (ror1/2/4/8, DPP/VALU-only) within
// 16-lane rows + one xor16 ds_swizzle level. Sum-equivalent to the xor tree.
__device__ __forceinline__ void wred2_32(double& a, double& b) {
  a += dpp_ror_d<0x121>(a);  b += dpp_ror_d<0x121>(b);   // ror:1
  a += dpp_ror_d<0x122>(a);  b += dpp_ror_d<0x122>(b);   // ror:2
  a += dpp_ror_d<0x124>(a);  b += dpp_ror_d<0x124>(b);   // ror:4
  a += dpp_ror_d<0x128>(a);  b += dpp_ror_d<0x128>(b);   // ror:8
  a += swz_xor16_d(a);       b += swz_xor16_d(b);        // xor:16 (within 32)
}
__device__ __forceinline__ double dot4d(const float4 a, const float4 b) {
  return (double)a.x*(double)b.x + (double)a.y*(double)b.y
       + (double)a.z*(double)b.z + (double)a.w*(double)b.w;
}
// dot of pre-converted f64 x (8 elems) against two f32x4 halves of a codeword
__device__ __forceinline__ double dot8dx(const double* xd, const f32x4 a, const f32x4 b) {
  return xd[0]*(double)a.x + xd[1]*(double)a.y + xd[2]*(double)a.z + xd[3]*(double)a.w
       + xd[4]*(double)b.x + xd[5]*(double)b.y + xd[6]*(double)b.z + xd[7]*(double)b.w;
}
__device__ __forceinline__ unsigned long long packf(float dist, int b) {
  // dist is always positive here -> f32 bit pattern is order-preserving.
  return ((unsigned long long)__float_as_uint(dist) << 32) | (unsigned int)b;
}

// ---------- ws layout (bytes, all 8B aligned) ----------
static constexpr size_t OFF_EN   = 0;                          // 1020 double
static constexpr size_t OFF_KLP  = OFF_EN   + 1020*8;          // 1020 double
static constexpr size_t OFF_PD   = OFF_KLP  + 1020*8;          // 262144 float2
static constexpr size_t OFF_STAB = OFF_PD   + (size_t)262144*8;// 65535 double
static constexpr size_t OFF_REC  = OFF_STAB + (size_t)65535*8; // 32 double
static constexpr size_t OFF_RCE  = OFF_REC  + 32*8;            // 32 double
static constexpr size_t OFF_RNC  = OFF_RCE  + 32*8;            // 24 double
static constexpr size_t OFF_RW   = OFF_RNC  + 24*8;            // 24 double
static constexpr size_t OFF_CNT  = OFF_RW   + 24*8;            // 1020 u32
static constexpr size_t OFF_IDX  = OFF_CNT  + 1020*4;          // 262144 int
static constexpr size_t OFF_NC   = OFF_IDX  + (size_t)262144*4;// 261120 float

// ---------- kernels ----------

// one wave per (m,node): node norms, kl partials, normalized codewords
__global__ __launch_bounds__(256) void k_prep(const float* __restrict__ tree,
    double* __restrict__ en, double* __restrict__ klp, float* __restrict__ nc) {
  int w = (int)((blockIdx.x*blockDim.x + threadIdx.x) >> 6);
  int lane = threadIdx.x & 63;
  if (w >= NM*NNODES) return;
  const float* row = tree + (size_t)w*(2*NL);
  float4 mu = ((const float4*)row)[lane];
  float4 lv = ((const float4*)(row + NL))[lane];
  double s2 = dot4d(mu, mu);
  double kp = exp((double)lv.x)+exp((double)lv.y)+exp((double)lv.z)+exp((double)lv.w)
            - (double)lv.x-(double)lv.y-(double)lv.z-(double)lv.w + s2 - 4.0;
  double s2t = s2, kpt = kp;
  wred2(s2t, kpt);
  double inv = 1.0 / fmax(sqrt(s2t), 1e-12);
  float4 o;
  o.x=(float)(mu.x*inv); o.y=(float)(mu.y*inv); o.z=(float)(mu.z*inv); o.w=(float)(mu.w*inv);
  ((float4*)(nc + (size_t)w*NL))[lane] = o;
  if (lane == 0) { en[w] = s2t; klp[w] = kpt; }
}

// TWO rows per wave (half-wave each, 8 floats/lane): walk the tree AND stream the
// selected codeword (z) out from registers (R8 structure — best measured).
// Reduction transport: DPP row_ror (VALU) + single ds_swizzle xor16 level.
__global__ __launch_bounds__(256) void k_decide(
    const float* __restrict__ xs, const float* __restrict__ tree,
    const double* __restrict__ en, float* __restrict__ out,
    int* __restrict__ idxws, float2* __restrict__ pd)
{
  int gw = (int)((blockIdx.x*blockDim.x + threadIdx.x) >> 6);
  int lane = threadIdx.x & 63;
  int half = lane >> 5, l = lane & 31;
  int row = gw*2 + half;
  if (row >= NM*NB) return;
  int m = row >> 13, b = row & (NB-1);
  const float* treem = tree + (size_t)m*NNODES*(2*NL);
  const double* enm  = en + m*NNODES;
  const f32x4* xr = (const f32x4*)(xs + (size_t)row*NL);
  f32x4 xa = __builtin_nontemporal_load(&xr[2*l]);
  f32x4 xb = __builtin_nontemporal_load(&xr[2*l+1]);
  double xd[8];
  xd[0]=(double)xa.x; xd[1]=(double)xa.y; xd[2]=(double)xa.z; xd[3]=(double)xa.w;
  xd[4]=(double)xb.x; xd[5]=(double)xb.y; xd[6]=(double)xb.z; xd[7]=(double)xb.w;
  const f32x4* e0r = (const f32x4*)treem;
  f32x4 za = e0r[2*l], zb = e0r[2*l+1];        // zprev = root codeword (depth 0)
  const f32x4* c1r = (const f32x4*)(treem + (size_t)(2*NL));
  const f32x4* c2r = (const f32x4*)(treem + (size_t)2*(2*NL));
  f32x4 v0a = c1r[2*l], v0b = c1r[2*l+1];
  f32x4 v1a = c2r[2*l], v1b = c2r[2*l+1];
  double xn = xd[0]*xd[0]+xd[1]*xd[1]+xd[2]*xd[2]+xd[3]*xd[3]
            + xd[4]*xd[4]+xd[5]*xd[5]+xd[6]*xd[6]+xd[7]*xd[7];
  double rr = dot8dx(xd, za, zb);
  wred2_32(xn, rr);
  double dd0 = xn + enm[0] - 2.0*rr;
  int oi = (m*NDEPTH)*NB + b;                    // depth-0 row index
  if (l == 0) { idxws[oi] = 0; pd[oi] = make_float2((float)dd0,(float)dd0); }
  int pk = 0;
  for (int d = 1; d < NDEPTH; ++d) {
    int n0 = (1 << d) - 1 + 2*pk;
    // (1) prefetch grandchildren for next depth
    f32x4 g0a,g0b,g1a,g1b,g2a,g2b,g3a,g3b;
    if (d < NDEPTH-1) {
      const float* gp = treem + (size_t)((1 << (d+1)) - 1 + 4*pk)*(2*NL);
      const f32x4* g0r = (const f32x4*)gp;
      const f32x4* g1r = (const f32x4*)(gp + 2*NL);
      const f32x4* g2r = (const f32x4*)(gp + 4*NL);
      const f32x4* g3r = (const f32x4*)(gp + 6*NL);
      g0a=g0r[2*l]; g0b=g0r[2*l+1];
      g1a=g1r[2*l]; g1b=g1r[2*l+1];
      g2a=g2r[2*l]; g2b=g2r[2*l+1];
      g3a=g3r[2*l]; g3b=g3r[2*l+1];
    }
    // (2) stream out z of the PREVIOUS depth from registers (nontemporal)
    {
      f32x4* zo = (f32x4*)(out + (size_t)ZBASE + (size_t)oi*NL);
      __builtin_nontemporal_store(za, &zo[2*l]);
      __builtin_nontemporal_store(zb, &zo[2*l+1]);
    }
    // (3) dots + reduction on current children
    double en0 = enm[n0], en1 = enm[n0+1];
    double r0 = dot8dx(xd, v0a, v0b);
    double r1 = dot8dx(xd, v1a, v1b);
    wred2_32(r0, r1);
    double d0 = xn + en0 - 2.0*r0;
    double d1 = xn + en1 - 2.0*r1;
    bool p1s = (d1 < d0);                 // tie -> even child, matches argmin
    int kc = 2*pk + (p1s ? 1 : 0);
    oi = (m*NDEPTH + d)*NB + b;
    if (l == 0) { idxws[oi] = kc; pd[oi] = make_float2((float)d0,(float)d1); }
    za = p1s ? v1a : v0a;  zb = p1s ? v1b : v0b;
    pk = kc;
    if (d < NDEPTH-1) {
      v0a = p1s ? g2a : g0a; v0b = p1s ? g2b : g0b;
      v1a = p1s ? g3a : g1a; v1b = p1s ? g3b : g1b;
    }
  }
  // final depth's z
  f32x4* zo = (f32x4*)(out + (size_t)ZBASE + (size_t)oi*NL);
  __builtin_nontemporal_store(za, &zo[2*l]);
  __builtin_nontemporal_store(zb, &zo[2*l+1]);
}

// Fused mid kernel: blocks 0..31 = per-(m,d) node stats (argmin/hist/ec/ce sums)
// + coalesced idx-float writes into out[]; blocks 32.. = s-table dots.
__global__ __launch_bounds__(256) void k_mid(
    const float* __restrict__ xs, const float* __restrict__ tree,
    const float2* __restrict__ pd, const int* __restrict__ idxws,
    const float* __restrict__ nc,
    unsigned int* __restrict__ cnt, double* __restrict__ rec,
    double* __restrict__ rce, double* __restrict__ stab,
    float* __restrict__ out)
{
  __shared__ unsigned long long nmin[128*8];
  __shared__ unsigned int hc[128*8];
  __shared__ double sh[256];
  int t = threadIdx.x;
  if (blockIdx.x < 32) {
    int bid = blockIdx.x; int m = bid >> 3, d = bid & 7;
    int K = 1 << d, off = K - 1;
    for (int i = t; i < K*8; i += 256) { nmin[i] = INFPACK; hc[i] = 0u; }
    __syncthreads();
    int st = t & 7;
    double a = 0;
    if (d == 0) {
      const float2* pp = pd + (size_t)(m*NDEPTH)*NB;
      float* ob = out + (size_t)(m*NDEPTH)*NB;
      for (int b = t; b < NB; b += 256) {
        float2 v = pp[b]; a += (double)v.x;
        atomicMin(&nmin[st], packf(v.x, b));
        ob[b] = 0.0f;
      }
    } else {
      const int* pidx = idxws + (m*NDEPTH + d - 1)*NB;
      const int* cidx = idxws + (m*NDEPTH + d)*NB;
      const float2* pp = pd + (size_t)(m*NDEPTH + d)*NB;
      float* ob = out + (size_t)(m*NDEPTH + d)*NB;
      for (int b = t; b < NB; b += 256) {
        int pk = pidx[b]; float2 v = pp[b];
        int cc = cidx[b];
        a += (double)fminf(v.x, v.y);
        atomicMin(&nmin[(2*pk  )*8 + st], packf(v.x, b));
        atomicMin(&nmin[(2*pk+1)*8 + st], packf(v.y, b));
        atomicAdd(&hc[cc*8 + st], 1u);
        ob[b] = (float)cc;
      }
    }
    sh[t] = a; __syncthreads();
    for (int s = 128; s > 0; s >>= 1) { if (t < s) sh[t] += sh[t+s]; __syncthreads(); }
    if (t == 0) rec[bid] = sh[0];
    for (int i = t; i < K; i += 256) {
      unsigned long long mn = nmin[i*8];
      unsigned int c = hc[i*8];
      #pragma unroll
      for (int s = 1; s < 8; ++s) { mn = min(mn, nmin[i*8+s]); c += hc[i*8+s]; }
      nmin[i*8] = mn;
      cnt[m*NNODES + off + i] = (d == 0) ? (unsigned)NB : c;
    }
    __syncthreads();
    int wv = t >> 6, ln = t & 63;
    for (int i = wv; i < K; i += 4) {
      unsigned int b2 = (unsigned int)(nmin[i*8] & 0xFFFFFFFFULL);
      const float4* xr = (const float4*)(xs + ((size_t)m*NB + b2)*NL);
      const float4* er = (const float4*)(tree + (size_t)(m*NNODES + off + i)*(2*NL));
      float4 xv = xr[ln], ev = er[ln];
      double dx=(double)xv.x-(double)ev.x, dy=(double)xv.y-(double)ev.y;
      double dz=(double)xv.z-(double)ev.z, dw=(double)xv.w-(double)ev.w;
      double s = wred(dx*dx + dy*dy + dz*dz + dw*dw);
      if (ln == 0) sh[i] = s;
    }
    __syncthreads();
    double c2 = (t < K) ? sh[t] : 0.0;
    __syncthreads();
    sh[t] = c2; __syncthreads();
    for (int s = 128; s > 0; s >>= 1) { if (t < s) sh[t] += sh[t+s]; __syncthreads(); }
    if (t == 0) rce[bid] = sh[0];
  } else {
    // s-table: one wave per (pair,d,i,j), grid-stride
    int wid0 = (int)((blockIdx.x - 32)*4 + (t >> 6));
    int lane = t & 63;
    int nw = (int)(gridDim.x - 32)*4;
    for (int w = wid0; w < 3*STAB_PP; w += nw) {
      int p = w / STAB_PP, r = w - p*STAB_PP;
      int d = 0;
      while (d < 7 && r >= c_pref[d+1]) ++d;
      int q = r - c_pref[d]; int K = 1 << d; int off = K - 1;
      int i = q >> d, j = q & (K - 1);
      float4 av = ((const float4*)(nc + (size_t)(p*NNODES + off + i)*NL))[lane];
      float4 bv = ((const float4*)(nc + (size_t)((p+1)*NNODES + off + j)*NL))[lane];
      double s = wred(dot4d(av, bv));
      if (lane == 0) stab[w] = s / 0.07;
    }
  }
}

// Fused tail: blocks 0..23 = nce (LSE + per-b sum), blocks 24..47 = wasserstein.
__global__ __launch_bounds__(256) void k_tail(const double* __restrict__ stab,
    const unsigned int* __restrict__ cnt, const int* __restrict__ idxws,
    double* __restrict__ rnc, double* __restrict__ rw) {
  int t = threadIdx.x;
  if (blockIdx.x < 24) {
    int bid = blockIdx.x; int d = bid / 3, p = bid % 3;
    int K = 1 << d, off = K - 1;
    __shared__ unsigned int cnl[128];
    __shared__ double lsel[128];
    __shared__ double sh[256];
    if (t < K) cnl[t] = cnt[(p+1)*NNODES + off + t];
    __syncthreads();
    const double* sb = stab + (size_t)p*STAB_PP + c_pref[d];
    if (t < K) {
      const double* srow = sb + (size_t)t*K;
      double mx = -1e300;
      for (int j = 0; j < K; ++j) if (cnl[j] > 0u) { double v = srow[j]; if (v > mx) mx = v; }
      double s = 0;
      for (int j = 0; j < K; ++j) if (cnl[j] > 0u) s += (double)cnl[j]*exp(srow[j] - mx);
      lsel[t] = mx + log(s);
    }
    __syncthreads();
    const int* im  = idxws + (p*NDEPTH + d)*NB;
    const int* in_ = idxws + ((p+1)*NDEPTH + d)*NB;
    double a = 0;
    for (int b = t; b < NB; b += 256) {
      int cm = im[b], cn2 = in_[b];
      a += sb[(size_t)cm*K + cn2] - lsel[cm];
    }
    sh[t] = a; __syncthreads();
    for (int s = 128; s > 0; s >>= 1) { if (t < s) sh[t] += sh[t+s]; __syncthreads(); }
    if (t == 0) rnc[bid] = sh[0];
  } else {
    int bid = blockIdx.x - 24; int d = bid / 3, p = bid % 3;
    int K = 1 << d, off = K - 1;
    __shared__ double A[128], Bv[128], Rd[128];
    __shared__ double Wsh;
    if (t < 128) {
      A[t]  = (t < K) ? (double)cnt[p*NNODES + off + t]     : 0.0;
      Bv[t] = (t < K) ? (double)cnt[(p+1)*NNODES + off + t] : 0.0;
    }
    if (t == 0) Wsh = 0.0;
    __syncthreads();
    if (t < 128) Rd[t] = A[t];
    __syncthreads();
    for (int s = 64; s > 0; s >>= 1) { if (t < s) Rd[t] += Rd[t+s]; __syncthreads(); }
    double s1 = Rd[0];
    __syncthreads();
    if (t < 128) Rd[t] = Bv[t];
    __syncthreads();
    for (int s = 64; s > 0; s >>= 1) { if (t < s) Rd[t] += Rd[t+s]; __syncthreads(); }
    double s2 = Rd[0];
    __syncthreads();
    double i1 = 1.0/(s1 + 1e-8), i2 = 1.0/(s2 + 1e-8);
    if (t < K) { A[t] *= i1; Bv[t] *= i2; }
    __syncthreads();
    for (int n = K; n > 1; n >>= 1) {
      if (t < 128) Rd[t] = (t < n) ? fabs(A[t] - Bv[t]) : 0.0;
      __syncthreads();
      for (int s = 64; s > 0; s >>= 1) { if (t < s) Rd[t] += Rd[t+s]; __syncthreads(); }
      if (t == 0) Wsh += Rd[0];
      int h = n >> 1;
      double na = 0, nb = 0;
      if (t < h) { na = A[2*t] + A[2*t+1]; nb = Bv[2*t] + Bv[2*t+1]; }
      __syncthreads();
      if (t < h) { A[t] = na; Bv[t] = nb; }
      __syncthreads();
    }
    if (t == 0) rw[bid] = Wsh;
  }
}

// final scalar assembly
__global__ __launch_bounds__(256) void k_final(const double* __restrict__ klp,
    const double* __restrict__ rec, const double* __restrict__ rce,
    const double* __restrict__ rnc, const double* __restrict__ rw,
    float* __restrict__ out) {
  __shared__ double sh[256];
  int t = threadIdx.x;
  double a = 0;
  for (int i = t; i < NM*NNODES; i += 256) a += klp[i];
  sh[t] = a; __syncthreads();
  for (int s = 128; s > 0; s >>= 1) { if (t < s) sh[t] += sh[t+s]; __syncthreads(); }
  if (t == 0) {
    double kl = 0.5*sh[0] / ((double)NM*NNODES*NL);
    double vq = 0;
    for (int m = 0; m < NM; ++m)
      for (int d = 0; d < NDEPTH; ++d) {
        double K = (double)(1 << d);
        vq += 2.0*rec[m*NDEPTH + d]/((double)NB*NL)
            + 2.0*rce[m*NDEPTH + d]/(K*(double)NL);
      }
    double align = 0;
    for (int d = 0; d < NDEPTH; ++d)
      for (int p = 0; p < 3; ++p)
        align += rw[d*3 + p] - rnc[d*3 + p]/(double)NB;
    out[TOTAL_IDX] = (float)(vq + kl + align);
  }
}

extern "C" void kernel_launch(void* const* d_in, const int* in_sizes, int n_in,
                              void* d_out, int out_size, void* d_ws, size_t ws_size,
                              hipStream_t stream) {
  (void)in_sizes; (void)n_in; (void)out_size; (void)ws_size;
  const float* xs   = (const float*)d_in[0];   // (4, 8192, 256) f32
  const float* tree = (const float*)d_in[1];   // (4, 255, 512) f32
  float* out = (float*)d_out;
  char* ws = (char*)d_ws;

  double* en   = (double*)(ws + OFF_EN);
  double* klp  = (double*)(ws + OFF_KLP);
  float2* pd   = (float2*)(ws + OFF_PD);
  double* stab = (double*)(ws + OFF_STAB);
  double* rec  = (double*)(ws + OFF_REC);
  double* rce  = (double*)(ws + OFF_RCE);
  double* rnc  = (double*)(ws + OFF_RNC);
  double* rw   = (double*)(ws + OFF_RW);
  unsigned int* cnt = (unsigned int*)(ws + OFF_CNT);
  int* idxws   = (int*)(ws + OFF_IDX);
  float* nc    = (float*)(ws + OFF_NC);

  k_prep   <<<255, 256, 0, stream>>>(tree, en, klp, nc);
  k_decide <<<4096, 256, 0, stream>>>(xs, tree, en, out, idxws, pd);
  k_mid    <<<2048, 256, 0, stream>>>(xs, tree, pd, idxws, nc, cnt, rec, rce, stab, out);
  k_tail   <<<48, 256, 0, stream>>>(stab, cnt, idxws, rnc, rw);
  k_final  <<<1, 256, 0, stream>>>(klp, rec, rce, rnc, rw, out);
}

// Round 11
// 187.737 us; speedup vs baseline: 1.3245x; 1.3245x over previous
//
#include <hip/hip_runtime.h>

// Problem constants (match reference)
#define NM     4
#define NDEPTH 8
#define NL     256
#define NB     8192
#define NNODES 255            // 2^8 - 1
#define STAB_PP 21845         // sum_{d<8} 4^d
#define ZBASE  (NM*NDEPTH*NB)                 // 262144 (idx region size)
#define TOTAL_IDX (ZBASE + (size_t)NM*NDEPTH*NB*NL)  // 67371008
#define INFPACK (0x7F800000ULL << 32)
#define NROWS (NM*NDEPTH*NB)  // 262144
#define CACHED_NODES 31       // depths 0..4 in LDS
#define NODE_WS 288           // 256 words + 32 pad words (swizzle padding)

typedef float f32x4 __attribute__((ext_vector_type(4)));

__device__ __constant__ int c_pref[8] = {0,1,5,21,85,341,1365,5461}; // (4^d-1)/3

// ---------- helpers ----------
__device__ __forceinline__ double wred(double v) {
  v += __shfl_xor(v, 1, 64);
  v += __shfl_xor(v, 2, 64);
  v += __shfl_xor(v, 4, 64);
  v += __shfl_xor(v, 8, 64);
  v += __shfl_xor(v, 16, 64);
  v += __shfl_xor(v, 32, 64);
  return v;
}
__device__ __forceinline__ void wred2(double& a, double& b) {
  #pragma unroll
  for (int m = 1; m <= 32; m <<= 1) {
    double ta = __shfl_xor(a, m, 64);
    double tb = __shfl_xor(b, m, 64);
    a += ta; b += tb;
  }
}
// width-32 dual reduction (serves 2 rows per wave) — R8-proven shfl_xor form
__device__ __forceinline__ void wred2_32(double& a, double& b) {
  #pragma unroll
  for (int m = 1; m <= 16; m <<= 1) {
    double ta = __shfl_xor(a, m, 32);
    double tb = __shfl_xor(b, m, 32);
    a += ta; b += tb;
  }
}
__device__ __forceinline__ double dot4d(const float4 a, const float4 b) {
  return (double)a.x*(double)b.x + (double)a.y*(double)b.y
       + (double)a.z*(double)b.z + (double)a.w*(double)b.w;
}
// dot of pre-converted f64 x (8 elems) against two f32x4 halves of a codeword
__device__ __forceinline__ double dot8dx(const double* xd, const f32x4 a, const f32x4 b) {
  return xd[0]*(double)a.x + xd[1]*(double)a.y + xd[2]*(double)a.z + xd[3]*(double)a.w
       + xd[4]*(double)b.x + xd[5]*(double)b.y + xd[6]*(double)b.z + xd[7]*(double)b.w;
}
__device__ __forceinline__ unsigned long long packf(float dist, int b) {
  // dist is always positive here -> f32 bit pattern is order-preserving.
  return ((unsigned long long)__float_as_uint(dist) << 32) | (unsigned int)b;
}

// ---------- ws layout (bytes, all 8B aligned) ----------
static constexpr size_t OFF_EN   = 0;                          // 1020 double
static constexpr size_t OFF_KLP  = OFF_EN   + 1020*8;          // 1020 double
static constexpr size_t OFF_PD   = OFF_KLP  + 1020*8;          // 262144 float2
static constexpr size_t OFF_STAB = OFF_PD   + (size_t)262144*8;// 65535 double
static constexpr size_t OFF_REC  = OFF_STAB + (size_t)65535*8; // 32 double
static constexpr size_t OFF_RCE  = OFF_REC  + 32*8;            // 32 double
static constexpr size_t OFF_RNC  = OFF_RCE  + 32*8;            // 24 double
static constexpr size_t OFF_RW   = OFF_RNC  + 24*8;            // 24 double
static constexpr size_t OFF_CNT  = OFF_RW   + 24*8;            // 1020 u32
static constexpr size_t OFF_IDX  = OFF_CNT  + 1020*4;          // 262144 int
static constexpr size_t OFF_NC   = OFF_IDX  + (size_t)262144*4;// 261120 float

// ---------- kernels ----------

// one wave per (m,node): node norms, kl partials, normalized codewords
__global__ __launch_bounds__(256) void k_prep(const float* __restrict__ tree,
    double* __restrict__ en, double* __restrict__ klp, float* __restrict__ nc) {
  int w = (int)((blockIdx.x*blockDim.x + threadIdx.x) >> 6);
  int lane = threadIdx.x & 63;
  if (w >= NM*NNODES) return;
  const float* row = tree + (size_t)w*(2*NL);
  float4 mu = ((const float4*)row)[lane];
  float4 lv = ((const float4*)(row + NL))[lane];
  double s2 = dot4d(mu, mu);
  double kp = exp((double)lv.x)+exp((double)lv.y)+exp((double)lv.z)+exp((double)lv.w)
            - (double)lv.x-(double)lv.y-(double)lv.z-(double)lv.w + s2 - 4.0;
  double s2t = s2, kpt = kp;
  wred2(s2t, kpt);
  double inv = 1.0 / fmax(sqrt(s2t), 1e-12);
  float4 o;
  o.x=(float)(mu.x*inv); o.y=(float)(mu.y*inv); o.z=(float)(mu.z*inv); o.w=(float)(mu.w*inv);
  ((float4*)(nc + (size_t)w*NL))[lane] = o;
  if (lane == 0) { en[w] = s2t; klp[w] = kpt; }
}

// R8 structure + LDS tree cache for depths 0..4. 256 threads/block, 32 rows per
// block in 4 passes (2 rows per wave, half-wave each, 8 floats/lane). The
// speculation pattern is unchanged: grandchildren for depths 2..4 are read
// speculatively from LDS at the same point where R8 issued global loads;
// depths 5..7 keep the global prefetch path. Global gather/row: 27KB -> 13KB.
__global__ __launch_bounds__(256) void k_decide(
    const float* __restrict__ xs, const float* __restrict__ tree,
    const double* __restrict__ en, float* __restrict__ out,
    int* __restrict__ idxws, float2* __restrict__ pd)
{
  __shared__ float s_tree[CACHED_NODES * NODE_WS];   // 35,712 B
  int t = threadIdx.x;
  int blk = blockIdx.x;
  int m = (int)(((unsigned)blk * 32) >> 13);
  const float* treem = tree + (size_t)m*NNODES*(2*NL);
  // fill: 31 nodes x 64 f32x4; swizzle: word w -> w + ((w>>5)<<2)
  for (int j = t; j < CACHED_NODES*64; j += 256) {
    int node = j >> 6, w4 = j & 63;
    f32x4 v = *(const f32x4*)(treem + (size_t)node*(2*NL) + w4*4);
    *(f32x4*)&s_tree[node*NODE_WS + w4*4 + ((w4 >> 3) << 2)] = v;
  }
  __syncthreads();

  int wv = t >> 6;
  int lane = t & 63;
  int half = lane >> 5, l = lane & 31;
  int lofs = l*8 + ((l >> 2) << 2);     // per-lane swizzled word offset in a node
  const double* enm = en + m*NNODES;

  for (int p = 0; p < 4; ++p) {
    int row = blk*32 + p*8 + wv*2 + half;
    int b = row & (NB-1);
    const f32x4* xr = (const f32x4*)(xs + (size_t)row*NL);
    f32x4 xa = __builtin_nontemporal_load(&xr[2*l]);
    f32x4 xb = __builtin_nontemporal_load(&xr[2*l+1]);
    double xd[8];
    xd[0]=(double)xa.x; xd[1]=(double)xa.y; xd[2]=(double)xa.z; xd[3]=(double)xa.w;
    xd[4]=(double)xb.x; xd[5]=(double)xb.y; xd[6]=(double)xb.z; xd[7]=(double)xb.w;
    f32x4 za  = *(const f32x4*)&s_tree[lofs];
    f32x4 zb  = *(const f32x4*)&s_tree[lofs + 4];
    f32x4 v0a = *(const f32x4*)&s_tree[NODE_WS + lofs];
    f32x4 v0b = *(const f32x4*)&s_tree[NODE_WS + lofs + 4];
    f32x4 v1a = *(const f32x4*)&s_tree[2*NODE_WS + lofs];
    f32x4 v1b = *(const f32x4*)&s_tree[2*NODE_WS + lofs + 4];
    double xn = xd[0]*xd[0]+xd[1]*xd[1]+xd[2]*xd[2]+xd[3]*xd[3]
              + xd[4]*xd[4]+xd[5]*xd[5]+xd[6]*xd[6]+xd[7]*xd[7];
    double rr = dot8dx(xd, za, zb);
    wred2_32(xn, rr);
    double dd0 = xn + enm[0] - 2.0*rr;
    int oi = (m*NDEPTH)*NB + b;
    if (l == 0) { idxws[oi] = 0; pd[oi] = make_float2((float)dd0,(float)dd0); }
    int pk = 0;
    #pragma unroll
    for (int d = 1; d < NDEPTH; ++d) {
      // (1) speculative grandchildren for next depth: LDS if nodes <= 30, else global
      f32x4 g0a,g0b,g1a,g1b,g2a,g2b,g3a,g3b;
      if (d <= 3) {
        int gb = ((1 << (d+1)) - 1 + 4*pk) * NODE_WS;
        g0a = *(const f32x4*)&s_tree[gb + lofs];
        g0b = *(const f32x4*)&s_tree[gb + lofs + 4];
        g1a = *(const f32x4*)&s_tree[gb + NODE_WS + lofs];
        g1b = *(const f32x4*)&s_tree[gb + NODE_WS + lofs + 4];
        g2a = *(const f32x4*)&s_tree[gb + 2*NODE_WS + lofs];
        g2b = *(const f32x4*)&s_tree[gb + 2*NODE_WS + lofs + 4];
        g3a = *(const f32x4*)&s_tree[gb + 3*NODE_WS + lofs];
        g3b = *(const f32x4*)&s_tree[gb + 3*NODE_WS + lofs + 4];
      } else if (d < NDEPTH-1) {
        const float* gp = treem + (size_t)((1 << (d+1)) - 1 + 4*pk)*(2*NL);
        const f32x4* g0r = (const f32x4*)gp;
        const f32x4* g1r = (const f32x4*)(gp + 2*NL);
        const f32x4* g2r = (const f32x4*)(gp + 4*NL);
        const f32x4* g3r = (const f32x4*)(gp + 6*NL);
        g0a=g0r[2*l]; g0b=g0r[2*l+1];
        g1a=g1r[2*l]; g1b=g1r[2*l+1];
        g2a=g2r[2*l]; g2b=g2r[2*l+1];
        g3a=g3r[2*l]; g3b=g3r[2*l+1];
      }
      // (2) stream out z of the PREVIOUS depth from registers (nontemporal)
      {
        f32x4* zo = (f32x4*)(out + (size_t)ZBASE + (size_t)oi*NL);
        __builtin_nontemporal_store(za, &zo[2*l]);
        __builtin_nontemporal_store(zb, &zo[2*l+1]);
      }
      // (3) dots + reduction on current children
      int n0 = (1 << d) - 1 + 2*pk;
      double en0 = enm[n0], en1 = enm[n0+1];
      double r0 = dot8dx(xd, v0a, v0b);
      double r1 = dot8dx(xd, v1a, v1b);
      wred2_32(r0, r1);
      double d0 = xn + en0 - 2.0*r0;
      double d1 = xn + en1 - 2.0*r1;
      bool p1s = (d1 < d0);                 // tie -> even child, matches argmin
      int kc = 2*pk + (p1s ? 1 : 0);
      oi = (m*NDEPTH + d)*NB + b;
      if (l == 0) { idxws[oi] = kc; pd[oi] = make_float2((float)d0,(float)d1); }
      za = p1s ? v1a : v0a;  zb = p1s ? v1b : v0b;
      pk = kc;
      if (d < NDEPTH-1) {
        v0a = p1s ? g2a : g0a; v0b = p1s ? g2b : g0b;
        v1a = p1s ? g3a : g1a; v1b = p1s ? g3b : g1b;
      }
    }
    // final depth's z
    f32x4* zo = (f32x4*)(out + (size_t)ZBASE + (size_t)oi*NL);
    __builtin_nontemporal_store(za, &zo[2*l]);
    __builtin_nontemporal_store(zb, &zo[2*l+1]);
  }
}

// Fused mid kernel: blocks 0..31 = per-(m,d) node stats (argmin/hist/ec/ce sums)
// + coalesced idx-float writes into out[]; blocks 32.. = s-table dots.
__global__ __launch_bounds__(256) void k_mid(
    const float* __restrict__ xs, const float* __restrict__ tree,
    const float2* __restrict__ pd, const int* __restrict__ idxws,
    const float* __restrict__ nc,
    unsigned int* __restrict__ cnt, double* __restrict__ rec,
    double* __restrict__ rce, double* __restrict__ stab,
    float* __restrict__ out)
{
  __shared__ unsigned long long nmin[128*8];
  __shared__ unsigned int hc[128*8];
  __shared__ double sh[256];
  int t = threadIdx.x;
  if (blockIdx.x < 32) {
    int bid = blockIdx.x; int m = bid >> 3, d = bid & 7;
    int K = 1 << d, off = K - 1;
    for (int i = t; i < K*8; i += 256) { nmin[i] = INFPACK; hc[i] = 0u; }
    __syncthreads();
    int st = t & 7;
    double a = 0;
    if (d == 0) {
      const float2* pp = pd + (size_t)(m*NDEPTH)*NB;
      float* ob = out + (size_t)(m*NDEPTH)*NB;
      for (int b = t; b < NB; b += 256) {
        float2 v = pp[b]; a += (double)v.x;
        atomicMin(&nmin[st], packf(v.x, b));
        ob[b] = 0.0f;
      }
    } else {
      const int* pidx = idxws + (m*NDEPTH + d - 1)*NB;
      const int* cidx = idxws + (m*NDEPTH + d)*NB;
      const float2* pp = pd + (size_t)(m*NDEPTH + d)*NB;
      float* ob = out + (size_t)(m*NDEPTH + d)*NB;
      for (int b = t; b < NB; b += 256) {
        int pk = pidx[b]; float2 v = pp[b];
        int cc = cidx[b];
        a += (double)fminf(v.x, v.y);
        atomicMin(&nmin[(2*pk  )*8 + st], packf(v.x, b));
        atomicMin(&nmin[(2*pk+1)*8 + st], packf(v.y, b));
        atomicAdd(&hc[cc*8 + st], 1u);
        ob[b] = (float)cc;
      }
    }
    sh[t] = a; __syncthreads();
    for (int s = 128; s > 0; s >>= 1) { if (t < s) sh[t] += sh[t+s]; __syncthreads(); }
    if (t == 0) rec[bid] = sh[0];
    for (int i = t; i < K; i += 256) {
      unsigned long long mn = nmin[i*8];
      unsigned int c = hc[i*8];
      #pragma unroll
      for (int s = 1; s < 8; ++s) { mn = min(mn, nmin[i*8+s]); c += hc[i*8+s]; }
      nmin[i*8] = mn;
      cnt[m*NNODES + off + i] = (d == 0) ? (unsigned)NB : c;
    }
    __syncthreads();
    int wv = t >> 6, ln = t & 63;
    for (int i = wv; i < K; i += 4) {
      unsigned int b2 = (unsigned int)(nmin[i*8] & 0xFFFFFFFFULL);
      const float4* xr = (const float4*)(xs + ((size_t)m*NB + b2)*NL);
      const float4* er = (const float4*)(tree + (size_t)(m*NNODES + off + i)*(2*NL));
      float4 xv = xr[ln], ev = er[ln];
      double dx=(double)xv.x-(double)ev.x, dy=(double)xv.y-(double)ev.y;
      double dz=(double)xv.z-(double)ev.z, dw=(double)xv.w-(double)ev.w;
      double s = wred(dx*dx + dy*dy + dz*dz + dw*dw);
      if (ln == 0) sh[i] = s;
    }
    __syncthreads();
    double c2 = (t < K) ? sh[t] : 0.0;
    __syncthreads();
    sh[t] = c2; __syncthreads();
    for (int s = 128; s > 0; s >>= 1) { if (t < s) sh[t] += sh[t+s]; __syncthreads(); }
    if (t == 0) rce[bid] = sh[0];
  } else {
    // s-table: one wave per (pair,d,i,j), grid-stride
    int wid0 = (int)((blockIdx.x - 32)*4 + (t >> 6));
    int lane = t & 63;
    int nw = (int)(gridDim.x - 32)*4;
    for (int w = wid0; w < 3*STAB_PP; w += nw) {
      int p = w / STAB_PP, r = w - p*STAB_PP;
      int d = 0;
      while (d < 7 && r >= c_pref[d+1]) ++d;
      int q = r - c_pref[d]; int K = 1 << d; int off = K - 1;
      int i = q >> d, j = q & (K - 1);
      float4 av = ((const float4*)(nc + (size_t)(p*NNODES + off + i)*NL))[lane];
      float4 bv = ((const float4*)(nc + (size_t)((p+1)*NNODES + off + j)*NL))[lane];
      double s = wred(dot4d(av, bv));
      if (lane == 0) stab[w] = s / 0.07;
    }
  }
}

// Fused tail: blocks 0..23 = nce (LSE + per-b sum), blocks 24..47 = wasserstein.
__global__ __launch_bounds__(256) void k_tail(const double* __restrict__ stab,
    const unsigned int* __restrict__ cnt, const int* __restrict__ idxws,
    double* __restrict__ rnc, double* __restrict__ rw) {
  int t = threadIdx.x;
  if (blockIdx.x < 24) {
    int bid = blockIdx.x; int d = bid / 3, p = bid % 3;
    int K = 1 << d, off = K - 1;
    __shared__ unsigned int cnl[128];
    __shared__ double lsel[128];
    __shared__ double sh[256];
    if (t < K) cnl[t] = cnt[(p+1)*NNODES + off + t];
    __syncthreads();
    const double* sb = stab + (size_t)p*STAB_PP + c_pref[d];
    if (t < K) {
      const double* srow = sb + (size_t)t*K;
      double mx = -1e300;
      for (int j = 0; j < K; ++j) if (cnl[j] > 0u) { double v = srow[j]; if (v > mx) mx = v; }
      double s = 0;
      for (int j = 0; j < K; ++j) if (cnl[j] > 0u) s += (double)cnl[j]*exp(srow[j] - mx);
      lsel[t] = mx + log(s);
    }
    __syncthreads();
    const int* im  = idxws + (p*NDEPTH + d)*NB;
    const int* in_ = idxws + ((p+1)*NDEPTH + d)*NB;
    double a = 0;
    for (int b = t; b < NB; b += 256) {
      int cm = im[b], cn2 = in_[b];
      a += sb[(size_t)cm*K + cn2] - lsel[cm];
    }
    sh[t] = a; __syncthreads();
    for (int s = 128; s > 0; s >>= 1) { if (t < s) sh[t] += sh[t+s]; __syncthreads(); }
    if (t == 0) rnc[bid] = sh[0];
  } else {
    int bid = blockIdx.x - 24; int d = bid / 3, p = bid % 3;
    int K = 1 << d, off = K - 1;
    __shared__ double A[128], Bv[128], Rd[128];
    __shared__ double Wsh;
    if (t < 128) {
      A[t]  = (t < K) ? (double)cnt[p*NNODES + off + t]     : 0.0;
      Bv[t] = (t < K) ? (double)cnt[(p+1)*NNODES + off + t] : 0.0;
    }
    if (t == 0) Wsh = 0.0;
    __syncthreads();
    if (t < 128) Rd[t] = A[t];
    __syncthreads();
    for (int s = 64; s > 0; s >>= 1) { if (t < s) Rd[t] += Rd[t+s]; __syncthreads(); }
    double s1 = Rd[0];
    __syncthreads();
    if (t < 128) Rd[t] = Bv[t];
    __syncthreads();
    for (int s = 64; s > 0; s >>= 1) { if (t < s) Rd[t] += Rd[t+s]; __syncthreads(); }
    double s2 = Rd[0];
    __syncthreads();
    double i1 = 1.0/(s1 + 1e-8), i2 = 1.0/(s2 + 1e-8);
    if (t < K) { A[t] *= i1; Bv[t] *= i2; }
    __syncthreads();
    for (int n = K; n > 1; n >>= 1) {
      if (t < 128) Rd[t] = (t < n) ? fabs(A[t] - Bv[t]) : 0.0;
      __syncthreads();
      for (int s = 64; s > 0; s >>= 1) { if (t < s) Rd[t] += Rd[t+s]; __syncthreads(); }
      if (t == 0) Wsh += Rd[0];
      int h = n >> 1;
      double na = 0, nb = 0;
      if (t < h) { na = A[2*t] + A[2*t+1]; nb = Bv[2*t] + Bv[2*t+1]; }
      __syncthreads();
      if (t < h) { A[t] = na; Bv[t] = nb; }
      __syncthreads();
    }
    if (t == 0) rw[bid] = Wsh;
  }
}

// final scalar assembly
__global__ __launch_bounds__(256) void k_final(const double* __restrict__ klp,
    const double* __restrict__ rec, const double* __restrict__ rce,
    const double* __restrict__ rnc, const double* __restrict__ rw,
    float* __restrict__ out) {
  __shared__ double sh[256];
  int t = threadIdx.x;
  double a = 0;
  for (int i = t; i < NM*NNODES; i += 256) a += klp[i];
  sh[t] = a; __syncthreads();
  for (int s = 128; s > 0; s >>= 1) { if (t < s) sh[t] += sh[t+s]; __syncthreads(); }
  if (t == 0) {
    double kl = 0.5*sh[0] / ((double)NM*NNODES*NL);
    double vq = 0;
    for (int m = 0; m < NM; ++m)
      for (int d = 0; d < NDEPTH; ++d) {
        double K = (double)(1 << d);
        vq += 2.0*rec[m*NDEPTH + d]/((double)NB*NL)
            + 2.0*rce[m*NDEPTH + d]/(K*(double)NL);
      }
    double align = 0;
    for (int d = 0; d < NDEPTH; ++d)
      for (int p = 0; p < 3; ++p)
        align += rw[d*3 + p] - rnc[d*3 + p]/(double)NB;
    out[TOTAL_IDX] = (float)(vq + kl + align);
  }
}

extern "C" void kernel_launch(void* const* d_in, const int* in_sizes, int n_in,
                              void* d_out, int out_size, void* d_ws, size_t ws_size,
                              hipStream_t stream) {
  (void)in_sizes; (void)n_in; (void)out_size; (void)ws_size;
  const float* xs   = (const float*)d_in[0];   // (4, 8192, 256) f32
  const float* tree = (const float*)d_in[1];   // (4, 255, 512) f32
  float* out = (float*)d_out;
  char* ws = (char*)d_ws;

  double* en   = (double*)(ws + OFF_EN);
  double* klp  = (double*)(ws + OFF_KLP);
  float2* pd   = (float2*)(ws + OFF_PD);
  double* stab = (double*)(ws + OFF_STAB);
  double* rec  = (double*)(ws + OFF_REC);
  double* rce  = (double*)(ws + OFF_RCE);
  double* rnc  = (double*)(ws + OFF_RNC);
  double* rw   = (double*)(ws + OFF_RW);
  unsigned int* cnt = (unsigned int*)(ws + OFF_CNT);
  int* idxws   = (int*)(ws + OFF_IDX);
  float* nc    = (float*)(ws + OFF_NC);

  k_prep   <<<255, 256, 0, stream>>>(tree, en, klp, nc);
  k_decide <<<1024, 256, 0, stream>>>(xs, tree, en, out, idxws, pd);
  k_mid    <<<2048, 256, 0, stream>>>(xs, tree, pd, idxws, nc, cnt, rec, rce, stab, out);
  k_tail   <<<48, 256, 0, stream>>>(stab, cnt, idxws, rnc, rw);
  k_final  <<<1, 256, 0, stream>>>(klp, rec, rce, rnc, rw, out);
}

// Round 12
// 167.254 us; speedup vs baseline: 1.4867x; 1.1225x over previous
//
#include <hip/hip_runtime.h>

// Problem constants (match reference)
#define NM     4
#define NDEPTH 8
#define NL     256
#define NB     8192
#define NNODES 255            // 2^8 - 1
#define STAB_PP 21845         // sum_{d<8} 4^d
#define ZBASE  (NM*NDEPTH*NB)                 // 262144 (idx region size)
#define TOTAL_IDX (ZBASE + (size_t)NM*NDEPTH*NB*NL)  // 67371008
#define INFPACK (0x7F800000ULL << 32)
#define NROWS (NM*NDEPTH*NB)  // 262144
#define CACHED_NODES 31       // depths 0..4 in LDS
#define NODE_W 292            // words per cached node (256 + 36 pad -> bank spread)

typedef float f32x4 __attribute__((ext_vector_type(4)));

__device__ __constant__ int c_pref[8] = {0,1,5,21,85,341,1365,5461}; // (4^d-1)/3

// ---------- helpers ----------
__device__ __forceinline__ double wred(double v) {
  v += __shfl_xor(v, 1, 64);
  v += __shfl_xor(v, 2, 64);
  v += __shfl_xor(v, 4, 64);
  v += __shfl_xor(v, 8, 64);
  v += __shfl_xor(v, 16, 64);
  v += __shfl_xor(v, 32, 64);
  return v;
}
__device__ __forceinline__ void wred2(double& a, double& b) {
  #pragma unroll
  for (int m = 1; m <= 32; m <<= 1) {
    double ta = __shfl_xor(a, m, 64);
    double tb = __shfl_xor(b, m, 64);
    a += ta; b += tb;
  }
}
// width-16 dual reduction (serves 4 rows per wave): 4 levels
__device__ __forceinline__ void wred2_16(double& a, double& b) {
  #pragma unroll
  for (int m = 1; m <= 8; m <<= 1) {
    double ta = __shfl_xor(a, m, 16);
    double tb = __shfl_xor(b, m, 16);
    a += ta; b += tb;
  }
}
__device__ __forceinline__ double dot4d(const float4 a, const float4 b) {
  return (double)a.x*(double)b.x + (double)a.y*(double)b.y
       + (double)a.z*(double)b.z + (double)a.w*(double)b.w;
}
// dot of 16 pre-converted f64 x elems against 4 f32x4 codeword chunks
__device__ __forceinline__ double dot16dx(const double* xd,
    const f32x4 a, const f32x4 b, const f32x4 c, const f32x4 d) {
  return xd[0]*(double)a.x + xd[1]*(double)a.y + xd[2]*(double)a.z + xd[3]*(double)a.w
       + xd[4]*(double)b.x + xd[5]*(double)b.y + xd[6]*(double)b.z + xd[7]*(double)b.w
       + xd[8]*(double)c.x + xd[9]*(double)c.y + xd[10]*(double)c.z + xd[11]*(double)c.w
       + xd[12]*(double)d.x + xd[13]*(double)d.y + xd[14]*(double)d.z + xd[15]*(double)d.w;
}
__device__ __forceinline__ unsigned long long packf(float dist, int b) {
  // dist is always positive here -> f32 bit pattern is order-preserving.
  return ((unsigned long long)__float_as_uint(dist) << 32) | (unsigned int)b;
}

// ---------- ws layout (bytes, all 8B aligned) ----------
static constexpr size_t OFF_EN   = 0;                          // 1020 double
static constexpr size_t OFF_KLP  = OFF_EN   + 1020*8;          // 1020 double
static constexpr size_t OFF_PD   = OFF_KLP  + 1020*8;          // 262144 float2
static constexpr size_t OFF_STAB = OFF_PD   + (size_t)262144*8;// 65535 double
static constexpr size_t OFF_REC  = OFF_STAB + (size_t)65535*8; // 32 double
static constexpr size_t OFF_RCE  = OFF_REC  + 32*8;            // 32 double
static constexpr size_t OFF_RNC  = OFF_RCE  + 32*8;            // 24 double
static constexpr size_t OFF_RW   = OFF_RNC  + 24*8;            // 24 double
static constexpr size_t OFF_CNT  = OFF_RW   + 24*8;            // 1020 u32
static constexpr size_t OFF_IDX  = OFF_CNT  + 1020*4;          // 262144 int
static constexpr size_t OFF_NC   = OFF_IDX  + (size_t)262144*4;// 261120 float

// ---------- kernels ----------

// one wave per (m,node): node norms, kl partials, normalized codewords
__global__ __launch_bounds__(256) void k_prep(const float* __restrict__ tree,
    double* __restrict__ en, double* __restrict__ klp, float* __restrict__ nc) {
  int w = (int)((blockIdx.x*blockDim.x + threadIdx.x) >> 6);
  int lane = threadIdx.x & 63;
  if (w >= NM*NNODES) return;
  const float* row = tree + (size_t)w*(2*NL);
  float4 mu = ((const float4*)row)[lane];
  float4 lv = ((const float4*)(row + NL))[lane];
  double s2 = dot4d(mu, mu);
  double kp = exp((double)lv.x)+exp((double)lv.y)+exp((double)lv.z)+exp((double)lv.w)
            - (double)lv.x-(double)lv.y-(double)lv.z-(double)lv.w + s2 - 4.0;
  double s2t = s2, kpt = kp;
  wred2(s2t, kpt);
  double inv = 1.0 / fmax(sqrt(s2t), 1e-12);
  float4 o;
  o.x=(float)(mu.x*inv); o.y=(float)(mu.y*inv); o.z=(float)(mu.z*inv); o.w=(float)(mu.w*inv);
  ((float4*)(nc + (size_t)w*NL))[lane] = o;
  if (lane == 0) { en[w] = s2t; klp[w] = kpt; }
}

// 16 lanes per row, 4 rows per wave, 16 rows per 256-thread block.
// Reduction: 4 shuffle levels (width 16). Tree depths 0..4 + en table in LDS;
// depths 5..7 candidates read from L2 after selection, issued BEFORE that
// depth's z-stores so vm-waits never drain the store queue. z streamed with
// nontemporal stores from registers.
__global__ __launch_bounds__(256) void k_decide(
    const float* __restrict__ xs, const float* __restrict__ tree,
    const double* __restrict__ en, float* __restrict__ out,
    int* __restrict__ idxws, float2* __restrict__ pd)
{
  __shared__ float s_tree[CACHED_NODES * NODE_W];   // 36,208 B
  __shared__ double s_en[NNODES];                   //  2,040 B
  int t = threadIdx.x;
  int blk = blockIdx.x;
  int m = (int)(((unsigned)blk * 16) >> 13);
  const float* treem = tree + (size_t)m*NNODES*(2*NL);
  for (int j = t; j < CACHED_NODES*64; j += 256) {
    int node = j >> 6, w4 = j & 63;
    *(f32x4*)&s_tree[node*NODE_W + w4*4] =
        *(const f32x4*)(treem + (size_t)node*(2*NL) + w4*4);
  }
  if (t < NNODES) s_en[t] = en[m*NNODES + t];
  __syncthreads();

  int wv = t >> 6, lane = t & 63;
  int g = lane >> 4, l = lane & 15;
  int row = blk*16 + wv*4 + g;
  int b = row & (NB-1);
  int lw = l*4;                       // word offset of this lane's first chunk

  // x: 4 f32x4 chunks at words lw + k*64 (nontemporal)
  const float* xrow = xs + (size_t)row*NL;
  f32x4 x0 = __builtin_nontemporal_load((const f32x4*)(xrow + lw));
  f32x4 x1 = __builtin_nontemporal_load((const f32x4*)(xrow + lw + 64));
  f32x4 x2 = __builtin_nontemporal_load((const f32x4*)(xrow + lw + 128));
  f32x4 x3 = __builtin_nontemporal_load((const f32x4*)(xrow + lw + 192));
  double xd[16];
  xd[0]=(double)x0.x; xd[1]=(double)x0.y; xd[2]=(double)x0.z; xd[3]=(double)x0.w;
  xd[4]=(double)x1.x; xd[5]=(double)x1.y; xd[6]=(double)x1.z; xd[7]=(double)x1.w;
  xd[8]=(double)x2.x; xd[9]=(double)x2.y; xd[10]=(double)x2.z; xd[11]=(double)x2.w;
  xd[12]=(double)x3.x; xd[13]=(double)x3.y; xd[14]=(double)x3.z; xd[15]=(double)x3.w;

  // depth 0: node 0 from LDS
  f32x4 e0 = *(const f32x4*)&s_tree[lw];
  f32x4 e1 = *(const f32x4*)&s_tree[lw + 64];
  f32x4 e2 = *(const f32x4*)&s_tree[lw + 128];
  f32x4 e3 = *(const f32x4*)&s_tree[lw + 192];
  double xn = xd[0]*xd[0]+xd[1]*xd[1]+xd[2]*xd[2]+xd[3]*xd[3]
            + xd[4]*xd[4]+xd[5]*xd[5]+xd[6]*xd[6]+xd[7]*xd[7]
            + xd[8]*xd[8]+xd[9]*xd[9]+xd[10]*xd[10]+xd[11]*xd[11]
            + xd[12]*xd[12]+xd[13]*xd[13]+xd[14]*xd[14]+xd[15]*xd[15];
  double rr = dot16dx(xd, e0, e1, e2, e3);
  wred2_16(xn, rr);
  double dd0 = xn + s_en[0] - 2.0*rr;
  int oi = (m*NDEPTH)*NB + b;
  if (l == 0) { idxws[oi] = 0; pd[oi] = make_float2((float)dd0,(float)dd0); }

  // load depth-1 candidates (nodes 1,2) from LDS
  f32x4 c0a = *(const f32x4*)&s_tree[1*NODE_W + lw];
  f32x4 c0b = *(const f32x4*)&s_tree[1*NODE_W + lw + 64];
  f32x4 c0c = *(const f32x4*)&s_tree[1*NODE_W + lw + 128];
  f32x4 c0d = *(const f32x4*)&s_tree[1*NODE_W + lw + 192];
  f32x4 c1a = *(const f32x4*)&s_tree[2*NODE_W + lw];
  f32x4 c1b = *(const f32x4*)&s_tree[2*NODE_W + lw + 64];
  f32x4 c1c = *(const f32x4*)&s_tree[2*NODE_W + lw + 128];
  f32x4 c1d = *(const f32x4*)&s_tree[2*NODE_W + lw + 192];

  // store z of depth 0 (node 0) — after depth-1 loads are issued
  {
    float* zo = out + (size_t)ZBASE + (size_t)oi*NL;
    __builtin_nontemporal_store(e0, (f32x4*)(zo + lw));
    __builtin_nontemporal_store(e1, (f32x4*)(zo + lw + 64));
    __builtin_nontemporal_store(e2, (f32x4*)(zo + lw + 128));
    __builtin_nontemporal_store(e3, (f32x4*)(zo + lw + 192));
  }

  int pk = 0;
  #pragma unroll
  for (int d = 1; d < NDEPTH; ++d) {
    int n0 = (1 << d) - 1 + 2*pk;
    double r0 = dot16dx(xd, c0a, c0b, c0c, c0d);
    double r1 = dot16dx(xd, c1a, c1b, c1c, c1d);
    wred2_16(r0, r1);
    double en0 = s_en[n0], en1 = s_en[n0+1];
    double d0 = xn + en0 - 2.0*r0;
    double d1 = xn + en1 - 2.0*r1;
    bool p1s = (d1 < d0);                 // tie -> even child, matches argmin
    int kc = 2*pk + (p1s ? 1 : 0);
    // copy selected codeword out of the candidate regs before they are reloaded
    f32x4 zs0 = p1s ? c1a : c0a;
    f32x4 zs1 = p1s ? c1b : c0b;
    f32x4 zs2 = p1s ? c1c : c0c;
    f32x4 zs3 = p1s ? c1d : c0d;
    oi = (m*NDEPTH + d)*NB + b;
    pk = kc;
    // issue next depth's candidate loads BEFORE this depth's z-stores
    if (d < NDEPTH-1) {
      int nn = (1 << (d+1)) - 1 + 2*pk;
      if (d + 1 <= 4) {
        c0a = *(const f32x4*)&s_tree[nn*NODE_W + lw];
        c0b = *(const f32x4*)&s_tree[nn*NODE_W + lw + 64];
        c0c = *(const f32x4*)&s_tree[nn*NODE_W + lw + 128];
        c0d = *(const f32x4*)&s_tree[nn*NODE_W + lw + 192];
        c1a = *(const f32x4*)&s_tree[(nn+1)*NODE_W + lw];
        c1b = *(const f32x4*)&s_tree[(nn+1)*NODE_W + lw + 64];
        c1c = *(const f32x4*)&s_tree[(nn+1)*NODE_W + lw + 128];
        c1d = *(const f32x4*)&s_tree[(nn+1)*NODE_W + lw + 192];
      } else {
        const float* n0p = treem + (size_t)nn*(2*NL);
        const float* n1p = n0p + 2*NL;
        c0a = *(const f32x4*)(n0p + lw);
        c0b = *(const f32x4*)(n0p + lw + 64);
        c0c = *(const f32x4*)(n0p + lw + 128);
        c0d = *(const f32x4*)(n0p + lw + 192);
        c1a = *(const f32x4*)(n1p + lw);
        c1b = *(const f32x4*)(n1p + lw + 64);
        c1c = *(const f32x4*)(n1p + lw + 128);
        c1d = *(const f32x4*)(n1p + lw + 192);
      }
    }
    // stream out this depth's z (nontemporal; younger than the loads above)
    {
      float* zo = out + (size_t)ZBASE + (size_t)oi*NL;
      __builtin_nontemporal_store(zs0, (f32x4*)(zo + lw));
      __builtin_nontemporal_store(zs1, (f32x4*)(zo + lw + 64));
      __builtin_nontemporal_store(zs2, (f32x4*)(zo + lw + 128));
      __builtin_nontemporal_store(zs3, (f32x4*)(zo + lw + 192));
    }
    if (l == 0) { idxws[oi] = kc; pd[oi] = make_float2((float)d0,(float)d1); }
  }
}

// Fused mid kernel: blocks 0..31 = per-(m,d) node stats (argmin/hist/ec/ce sums)
// + coalesced idx-float writes into out[]; blocks 32.. = s-table dots.
__global__ __launch_bounds__(256) void k_mid(
    const float* __restrict__ xs, const float* __restrict__ tree,
    const float2* __restrict__ pd, const int* __restrict__ idxws,
    const float* __restrict__ nc,
    unsigned int* __restrict__ cnt, double* __restrict__ rec,
    double* __restrict__ rce, double* __restrict__ stab,
    float* __restrict__ out)
{
  __shared__ unsigned long long nmin[128*8];
  __shared__ unsigned int hc[128*8];
  __shared__ double sh[256];
  int t = threadIdx.x;
  if (blockIdx.x < 32) {
    int bid = blockIdx.x; int m = bid >> 3, d = bid & 7;
    int K = 1 << d, off = K - 1;
    for (int i = t; i < K*8; i += 256) { nmin[i] = INFPACK; hc[i] = 0u; }
    __syncthreads();
    int st = t & 7;
    double a = 0;
    if (d == 0) {
      const float2* pp = pd + (size_t)(m*NDEPTH)*NB;
      float* ob = out + (size_t)(m*NDEPTH)*NB;
      for (int b = t; b < NB; b += 256) {
        float2 v = pp[b]; a += (double)v.x;
        atomicMin(&nmin[st], packf(v.x, b));
        ob[b] = 0.0f;
      }
    } else {
      const int* pidx = idxws + (m*NDEPTH + d - 1)*NB;
      const int* cidx = idxws + (m*NDEPTH + d)*NB;
      const float2* pp = pd + (size_t)(m*NDEPTH + d)*NB;
      float* ob = out + (size_t)(m*NDEPTH + d)*NB;
      for (int b = t; b < NB; b += 256) {
        int pk = pidx[b]; float2 v = pp[b];
        int cc = cidx[b];
        a += (double)fminf(v.x, v.y);
        atomicMin(&nmin[(2*pk  )*8 + st], packf(v.x, b));
        atomicMin(&nmin[(2*pk+1)*8 + st], packf(v.y, b));
        atomicAdd(&hc[cc*8 + st], 1u);
        ob[b] = (float)cc;
      }
    }
    sh[t] = a; __syncthreads();
    for (int s = 128; s > 0; s >>= 1) { if (t < s) sh[t] += sh[t+s]; __syncthreads(); }
    if (t == 0) rec[bid] = sh[0];
    for (int i = t; i < K; i += 256) {
      unsigned long long mn = nmin[i*8];
      unsigned int c = hc[i*8];
      #pragma unroll
      for (int s = 1; s < 8; ++s) { mn = min(mn, nmin[i*8+s]); c += hc[i*8+s]; }
      nmin[i*8] = mn;
      cnt[m*NNODES + off + i] = (d == 0) ? (unsigned)NB : c;
    }
    __syncthreads();
    int wv = t >> 6, ln = t & 63;
    for (int i = wv; i < K; i += 4) {
      unsigned int b2 = (unsigned int)(nmin[i*8] & 0xFFFFFFFFULL);
      const float4* xr = (const float4*)(xs + ((size_t)m*NB + b2)*NL);
      const float4* er = (const float4*)(tree + (size_t)(m*NNODES + off + i)*(2*NL));
      float4 xv = xr[ln], ev = er[ln];
      double dx=(double)xv.x-(double)ev.x, dy=(double)xv.y-(double)ev.y;
      double dz=(double)xv.z-(double)ev.z, dw=(double)xv.w-(double)ev.w;
      double s = wred(dx*dx + dy*dy + dz*dz + dw*dw);
      if (ln == 0) sh[i] = s;
    }
    __syncthreads();
    double c2 = (t < K) ? sh[t] : 0.0;
    __syncthreads();
    sh[t] = c2; __syncthreads();
    for (int s = 128; s > 0; s >>= 1) { if (t < s) sh[t] += sh[t+s]; __syncthreads(); }
    if (t == 0) rce[bid] = sh[0];
  } else {
    // s-table: one wave per (pair,d,i,j), grid-stride
    int wid0 = (int)((blockIdx.x - 32)*4 + (t >> 6));
    int lane = t & 63;
    int nw = (int)(gridDim.x - 32)*4;
    for (int w = wid0; w < 3*STAB_PP; w += nw) {
      int p = w / STAB_PP, r = w - p*STAB_PP;
      int d = 0;
      while (d < 7 && r >= c_pref[d+1]) ++d;
      int q = r - c_pref[d]; int K = 1 << d; int off = K - 1;
      int i = q >> d, j = q & (K - 1);
      float4 av = ((const float4*)(nc + (size_t)(p*NNODES + off + i)*NL))[lane];
      float4 bv = ((const float4*)(nc + (size_t)((p+1)*NNODES + off + j)*NL))[lane];
      double s = wred(dot4d(av, bv));
      if (lane == 0) stab[w] = s / 0.07;
    }
  }
}

// Fused tail: blocks 0..23 = nce (LSE + per-b sum), blocks 24..47 = wasserstein.
__global__ __launch_bounds__(256) void k_tail(const double* __restrict__ stab,
    const unsigned int* __restrict__ cnt, const int* __restrict__ idxws,
    double* __restrict__ rnc, double* __restrict__ rw) {
  int t = threadIdx.x;
  if (blockIdx.x < 24) {
    int bid = blockIdx.x; int d = bid / 3, p = bid % 3;
    int K = 1 << d, off = K - 1;
    __shared__ unsigned int cnl[128];
    __shared__ double lsel[128];
    __shared__ double sh[256];
    if (t < K) cnl[t] = cnt[(p+1)*NNODES + off + t];
    __syncthreads();
    const double* sb = stab + (size_t)p*STAB_PP + c_pref[d];
    if (t < K) {
      const double* srow = sb + (size_t)t*K;
      double mx = -1e300;
      for (int j = 0; j < K; ++j) if (cnl[j] > 0u) { double v = srow[j]; if (v > mx) mx = v; }
      double s = 0;
      for (int j = 0; j < K; ++j) if (cnl[j] > 0u) s += (double)cnl[j]*exp(srow[j] - mx);
      lsel[t] = mx + log(s);
    }
    __syncthreads();
    const int* im  = idxws + (p*NDEPTH + d)*NB;
    const int* in_ = idxws + ((p+1)*NDEPTH + d)*NB;
    double a = 0;
    for (int b = t; b < NB; b += 256) {
      int cm = im[b], cn2 = in_[b];
      a += sb[(size_t)cm*K + cn2] - lsel[cm];
    }
    sh[t] = a; __syncthreads();
    for (int s = 128; s > 0; s >>= 1) { if (t < s) sh[t] += sh[t+s]; __syncthreads(); }
    if (t == 0) rnc[bid] = sh[0];
  } else {
    int bid = blockIdx.x - 24; int d = bid / 3, p = bid % 3;
    int K = 1 << d, off = K - 1;
    __shared__ double A[128], Bv[128], Rd[128];
    __shared__ double Wsh;
    if (t < 128) {
      A[t]  = (t < K) ? (double)cnt[p*NNODES + off + t]     : 0.0;
      Bv[t] = (t < K) ? (double)cnt[(p+1)*NNODES + off + t] : 0.0;
    }
    if (t == 0) Wsh = 0.0;
    __syncthreads();
    if (t < 128) Rd[t] = A[t];
    __syncthreads();
    for (int s = 64; s > 0; s >>= 1) { if (t < s) Rd[t] += Rd[t+s]; __syncthreads(); }
    double s1 = Rd[0];
    __syncthreads();
    if (t < 128) Rd[t] = Bv[t];
    __syncthreads();
    for (int s = 64; s > 0; s >>= 1) { if (t < s) Rd[t] += Rd[t+s]; __syncthreads(); }
    double s2 = Rd[0];
    __syncthreads();
    double i1 = 1.0/(s1 + 1e-8), i2 = 1.0/(s2 + 1e-8);
    if (t < K) { A[t] *= i1; Bv[t] *= i2; }
    __syncthreads();
    for (int n = K; n > 1; n >>= 1) {
      if (t < 128) Rd[t] = (t < n) ? fabs(A[t] - Bv[t]) : 0.0;
      __syncthreads();
      for (int s = 64; s > 0; s >>= 1) { if (t < s) Rd[t] += Rd[t+s]; __syncthreads(); }
      if (t == 0) Wsh += Rd[0];
      int h = n >> 1;
      double na = 0, nb = 0;
      if (t < h) { na = A[2*t] + A[2*t+1]; nb = Bv[2*t] + Bv[2*t+1]; }
      __syncthreads();
      if (t < h) { A[t] = na; Bv[t] = nb; }
      __syncthreads();
    }
    if (t == 0) rw[bid] = Wsh;
  }
}

// final scalar assembly
__global__ __launch_bounds__(256) void k_final(const double* __restrict__ klp,
    const double* __restrict__ rec, const double* __restrict__ rce,
    const double* __restrict__ rnc, const double* __restrict__ rw,
    float* __restrict__ out) {
  __shared__ double sh[256];
  int t = threadIdx.x;
  double a = 0;
  for (int i = t; i < NM*NNODES; i += 256) a += klp[i];
  sh[t] = a; __syncthreads();
  for (int s = 128; s > 0; s >>= 1) { if (t < s) sh[t] += sh[t+s]; __syncthreads(); }
  if (t == 0) {
    double kl = 0.5*sh[0] / ((double)NM*NNODES*NL);
    double vq = 0;
    for (int m = 0; m < NM; ++m)
      for (int d = 0; d < NDEPTH; ++d) {
        double K = (double)(1 << d);
        vq += 2.0*rec[m*NDEPTH + d]/((double)NB*NL)
            + 2.0*rce[m*NDEPTH + d]/(K*(double)NL);
      }
    double align = 0;
    for (int d = 0; d < NDEPTH; ++d)
      for (int p = 0; p < 3; ++p)
        align += rw[d*3 + p] - rnc[d*3 + p]/(double)NB;
    out[TOTAL_IDX] = (float)(vq + kl + align);
  }
}

extern "C" void kernel_launch(void* const* d_in, const int* in_sizes, int n_in,
                              void* d_out, int out_size, void* d_ws, size_t ws_size,
                              hipStream_t stream) {
  (void)in_sizes; (void)n_in; (void)out_size; (void)ws_size;
  const float* xs   = (const float*)d_in[0];   // (4, 8192, 256) f32
  const float* tree = (const float*)d_in[1];   // (4, 255, 512) f32
  float* out = (float*)d_out;
  char* ws = (char*)d_ws;

  double* en   = (double*)(ws + OFF_EN);
  double* klp  = (double*)(ws + OFF_KLP);
  float2* pd   = (float2*)(ws + OFF_PD);
  double* stab = (double*)(ws + OFF_STAB);
  double* rec  = (double*)(ws + OFF_REC);
  double* rce  = (double*)(ws + OFF_RCE);
  double* rnc  = (double*)(ws + OFF_RNC);
  double* rw   = (double*)(ws + OFF_RW);
  unsigned int* cnt = (unsigned int*)(ws + OFF_CNT);
  int* idxws   = (int*)(ws + OFF_IDX);
  float* nc    = (float*)(ws + OFF_NC);

  k_prep   <<<255, 256, 0, stream>>>(tree, en, klp, nc);
  k_decide <<<2048, 256, 0, stream>>>(xs, tree, en, out, idxws, pd);
  k_mid    <<<2048, 256, 0, stream>>>(xs, tree, pd, idxws, nc, cnt, rec, rce, stab, out);
  k_tail   <<<48, 256, 0, stream>>>(stab, cnt, idxws, rnc, rw);
  k_final  <<<1, 256, 0, stream>>>(klp, rec, rce, rnc, rw, out);
}

// Round 13
// 166.594 us; speedup vs baseline: 1.4926x; 1.0040x over previous
//
#include <hip/hip_runtime.h>

// Problem constants (match reference)
#define NM     4
#define NDEPTH 8
#define NL     256
#define NB     8192
#define NNODES 255            // 2^8 - 1
#define STAB_PP 21845         // sum_{d<8} 4^d
#define ZBASE  (NM*NDEPTH*NB)                 // 262144 (idx region size)
#define TOTAL_IDX (ZBASE + (size_t)NM*NDEPTH*NB*NL)  // 67371008
#define INFPACK (0x7F800000ULL << 32)
#define NROWS (NM*NDEPTH*NB)  // 262144
#define CACHED_NODES 31       // depths 0..4 in LDS
#define NODE_W 292            // words per cached node (256 + 36 pad -> bank spread)

typedef float f32x4 __attribute__((ext_vector_type(4)));

__device__ __constant__ int c_pref[8] = {0,1,5,21,85,341,1365,5461}; // (4^d-1)/3

// ---------- helpers ----------
__device__ __forceinline__ double wred(double v) {
  v += __shfl_xor(v, 1, 64);
  v += __shfl_xor(v, 2, 64);
  v += __shfl_xor(v, 4, 64);
  v += __shfl_xor(v, 8, 64);
  v += __shfl_xor(v, 16, 64);
  v += __shfl_xor(v, 32, 64);
  return v;
}
__device__ __forceinline__ void wred2(double& a, double& b) {
  #pragma unroll
  for (int m = 1; m <= 32; m <<= 1) {
    double ta = __shfl_xor(a, m, 64);
    double tb = __shfl_xor(b, m, 64);
    a += ta; b += tb;
  }
}
// width-16 dual reduction (serves 4 rows per wave): 4 levels
__device__ __forceinline__ void wred2_16(double& a, double& b) {
  #pragma unroll
  for (int m = 1; m <= 8; m <<= 1) {
    double ta = __shfl_xor(a, m, 16);
    double tb = __shfl_xor(b, m, 16);
    a += ta; b += tb;
  }
}
__device__ __forceinline__ double dot4d(const float4 a, const float4 b) {
  return (double)a.x*(double)b.x + (double)a.y*(double)b.y
       + (double)a.z*(double)b.z + (double)a.w*(double)b.w;
}
// balanced-tree dot of 16 pre-converted f64 x elems against 4 f32x4 chunks:
// 8 independent mul+fma pairs, then 3 add levels — dependency depth ~5 vs 16.
__device__ __forceinline__ double dot16dx(const double* xd,
    const f32x4 a, const f32x4 b, const f32x4 c, const f32x4 d) {
  double s0 = xd[0]*(double)a.x + xd[1]*(double)a.y;
  double s1 = xd[2]*(double)a.z + xd[3]*(double)a.w;
  double s2 = xd[4]*(double)b.x + xd[5]*(double)b.y;
  double s3 = xd[6]*(double)b.z + xd[7]*(double)b.w;
  double s4 = xd[8]*(double)c.x + xd[9]*(double)c.y;
  double s5 = xd[10]*(double)c.z + xd[11]*(double)c.w;
  double s6 = xd[12]*(double)d.x + xd[13]*(double)d.y;
  double s7 = xd[14]*(double)d.z + xd[15]*(double)d.w;
  return ((s0 + s1) + (s2 + s3)) + ((s4 + s5) + (s6 + s7));
}
__device__ __forceinline__ unsigned long long packf(float dist, int b) {
  // dist is always positive here -> f32 bit pattern is order-preserving.
  return ((unsigned long long)__float_as_uint(dist) << 32) | (unsigned int)b;
}

// ---------- ws layout (bytes, all 8B aligned) ----------
static constexpr size_t OFF_EN   = 0;                          // 1020 double
static constexpr size_t OFF_KLP  = OFF_EN   + 1020*8;          // 1020 double
static constexpr size_t OFF_PD   = OFF_KLP  + 1020*8;          // 262144 float2
static constexpr size_t OFF_STAB = OFF_PD   + (size_t)262144*8;// 65535 double
static constexpr size_t OFF_REC  = OFF_STAB + (size_t)65535*8; // 32 double
static constexpr size_t OFF_RCE  = OFF_REC  + 32*8;            // 32 double
static constexpr size_t OFF_RNC  = OFF_RCE  + 32*8;            // 24 double
static constexpr size_t OFF_RW   = OFF_RNC  + 24*8;            // 24 double
static constexpr size_t OFF_CNT  = OFF_RW   + 24*8;            // 1020 u32
static constexpr size_t OFF_IDX  = OFF_CNT  + 1020*4;          // 262144 int
static constexpr size_t OFF_NC   = OFF_IDX  + (size_t)262144*4;// 261120 float

// ---------- kernels ----------

// one wave per (m,node): node norms, kl partials, normalized codewords
__global__ __launch_bounds__(256) void k_prep(const float* __restrict__ tree,
    double* __restrict__ en, double* __restrict__ klp, float* __restrict__ nc) {
  int w = (int)((blockIdx.x*blockDim.x + threadIdx.x) >> 6);
  int lane = threadIdx.x & 63;
  if (w >= NM*NNODES) return;
  const float* row = tree + (size_t)w*(2*NL);
  float4 mu = ((const float4*)row)[lane];
  float4 lv = ((const float4*)(row + NL))[lane];
  double s2 = dot4d(mu, mu);
  double kp = exp((double)lv.x)+exp((double)lv.y)+exp((double)lv.z)+exp((double)lv.w)
            - (double)lv.x-(double)lv.y-(double)lv.z-(double)lv.w + s2 - 4.0;
  double s2t = s2, kpt = kp;
  wred2(s2t, kpt);
  double inv = 1.0 / fmax(sqrt(s2t), 1e-12);
  float4 o;
  o.x=(float)(mu.x*inv); o.y=(float)(mu.y*inv); o.z=(float)(mu.z*inv); o.w=(float)(mu.w*inv);
  ((float4*)(nc + (size_t)w*NL))[lane] = o;
  if (lane == 0) { en[w] = s2t; klp[w] = kpt; }
}

// 16 lanes per row, 4 rows per wave, 16 rows per 256-thread block (R12 structure).
// This round: balanced-tree f64 dots (dependency depth ~5 vs 16).
__global__ __launch_bounds__(256) void k_decide(
    const float* __restrict__ xs, const float* __restrict__ tree,
    const double* __restrict__ en, float* __restrict__ out,
    int* __restrict__ idxws, float2* __restrict__ pd)
{
  __shared__ float s_tree[CACHED_NODES * NODE_W];   // 36,208 B
  __shared__ double s_en[NNODES];                   //  2,040 B
  int t = threadIdx.x;
  int blk = blockIdx.x;
  int m = (int)(((unsigned)blk * 16) >> 13);
  const float* treem = tree + (size_t)m*NNODES*(2*NL);
  for (int j = t; j < CACHED_NODES*64; j += 256) {
    int node = j >> 6, w4 = j & 63;
    *(f32x4*)&s_tree[node*NODE_W + w4*4] =
        *(const f32x4*)(treem + (size_t)node*(2*NL) + w4*4);
  }
  if (t < NNODES) s_en[t] = en[m*NNODES + t];
  __syncthreads();

  int wv = t >> 6, lane = t & 63;
  int g = lane >> 4, l = lane & 15;
  int row = blk*16 + wv*4 + g;
  int b = row & (NB-1);
  int lw = l*4;                       // word offset of this lane's first chunk

  // x: 4 f32x4 chunks at words lw + k*64 (nontemporal)
  const float* xrow = xs + (size_t)row*NL;
  f32x4 x0 = __builtin_nontemporal_load((const f32x4*)(xrow + lw));
  f32x4 x1 = __builtin_nontemporal_load((const f32x4*)(xrow + lw + 64));
  f32x4 x2 = __builtin_nontemporal_load((const f32x4*)(xrow + lw + 128));
  f32x4 x3 = __builtin_nontemporal_load((const f32x4*)(xrow + lw + 192));
  double xd[16];
  xd[0]=(double)x0.x; xd[1]=(double)x0.y; xd[2]=(double)x0.z; xd[3]=(double)x0.w;
  xd[4]=(double)x1.x; xd[5]=(double)x1.y; xd[6]=(double)x1.z; xd[7]=(double)x1.w;
  xd[8]=(double)x2.x; xd[9]=(double)x2.y; xd[10]=(double)x2.z; xd[11]=(double)x2.w;
  xd[12]=(double)x3.x; xd[13]=(double)x3.y; xd[14]=(double)x3.z; xd[15]=(double)x3.w;

  // depth 0: node 0 from LDS
  f32x4 e0 = *(const f32x4*)&s_tree[lw];
  f32x4 e1 = *(const f32x4*)&s_tree[lw + 64];
  f32x4 e2 = *(const f32x4*)&s_tree[lw + 128];
  f32x4 e3 = *(const f32x4*)&s_tree[lw + 192];
  // balanced-tree xn
  double xn;
  {
    double n0 = xd[0]*xd[0] + xd[1]*xd[1];
    double n1 = xd[2]*xd[2] + xd[3]*xd[3];
    double n2 = xd[4]*xd[4] + xd[5]*xd[5];
    double n3 = xd[6]*xd[6] + xd[7]*xd[7];
    double n4 = xd[8]*xd[8] + xd[9]*xd[9];
    double n5 = xd[10]*xd[10] + xd[11]*xd[11];
    double n6 = xd[12]*xd[12] + xd[13]*xd[13];
    double n7 = xd[14]*xd[14] + xd[15]*xd[15];
    xn = ((n0 + n1) + (n2 + n3)) + ((n4 + n5) + (n6 + n7));
  }
  double rr = dot16dx(xd, e0, e1, e2, e3);
  wred2_16(xn, rr);
  double dd0 = xn + s_en[0] - 2.0*rr;
  int oi = (m*NDEPTH)*NB + b;
  if (l == 0) { idxws[oi] = 0; pd[oi] = make_float2((float)dd0,(float)dd0); }

  // load depth-1 candidates (nodes 1,2) from LDS
  f32x4 c0a = *(const f32x4*)&s_tree[1*NODE_W + lw];
  f32x4 c0b = *(const f32x4*)&s_tree[1*NODE_W + lw + 64];
  f32x4 c0c = *(const f32x4*)&s_tree[1*NODE_W + lw + 128];
  f32x4 c0d = *(const f32x4*)&s_tree[1*NODE_W + lw + 192];
  f32x4 c1a = *(const f32x4*)&s_tree[2*NODE_W + lw];
  f32x4 c1b = *(const f32x4*)&s_tree[2*NODE_W + lw + 64];
  f32x4 c1c = *(const f32x4*)&s_tree[2*NODE_W + lw + 128];
  f32x4 c1d = *(const f32x4*)&s_tree[2*NODE_W + lw + 192];

  // store z of depth 0 (node 0) — after depth-1 loads are issued
  {
    float* zo = out + (size_t)ZBASE + (size_t)oi*NL;
    __builtin_nontemporal_store(e0, (f32x4*)(zo + lw));
    __builtin_nontemporal_store(e1, (f32x4*)(zo + lw + 64));
    __builtin_nontemporal_store(e2, (f32x4*)(zo + lw + 128));
    __builtin_nontemporal_store(e3, (f32x4*)(zo + lw + 192));
  }

  int pk = 0;
  #pragma unroll
  for (int d = 1; d < NDEPTH; ++d) {
    int n0 = (1 << d) - 1 + 2*pk;
    double r0 = dot16dx(xd, c0a, c0b, c0c, c0d);
    double r1 = dot16dx(xd, c1a, c1b, c1c, c1d);
    wred2_16(r0, r1);
    double en0 = s_en[n0], en1 = s_en[n0+1];
    double d0 = xn + en0 - 2.0*r0;
    double d1 = xn + en1 - 2.0*r1;
    bool p1s = (d1 < d0);                 // tie -> even child, matches argmin
    int kc = 2*pk + (p1s ? 1 : 0);
    // copy selected codeword out of the candidate regs before they are reloaded
    f32x4 zs0 = p1s ? c1a : c0a;
    f32x4 zs1 = p1s ? c1b : c0b;
    f32x4 zs2 = p1s ? c1c : c0c;
    f32x4 zs3 = p1s ? c1d : c0d;
    oi = (m*NDEPTH + d)*NB + b;
    pk = kc;
    // issue next depth's candidate loads BEFORE this depth's z-stores
    if (d < NDEPTH-1) {
      int nn = (1 << (d+1)) - 1 + 2*pk;
      if (d + 1 <= 4) {
        c0a = *(const f32x4*)&s_tree[nn*NODE_W + lw];
        c0b = *(const f32x4*)&s_tree[nn*NODE_W + lw + 64];
        c0c = *(const f32x4*)&s_tree[nn*NODE_W + lw + 128];
        c0d = *(const f32x4*)&s_tree[nn*NODE_W + lw + 192];
        c1a = *(const f32x4*)&s_tree[(nn+1)*NODE_W + lw];
        c1b = *(const f32x4*)&s_tree[(nn+1)*NODE_W + lw + 64];
        c1c = *(const f32x4*)&s_tree[(nn+1)*NODE_W + lw + 128];
        c1d = *(const f32x4*)&s_tree[(nn+1)*NODE_W + lw + 192];
      } else {
        const float* n0p = treem + (size_t)nn*(2*NL);
        const float* n1p = n0p + 2*NL;
        c0a = *(const f32x4*)(n0p + lw);
        c0b = *(const f32x4*)(n0p + lw + 64);
        c0c = *(const f32x4*)(n0p + lw + 128);
        c0d = *(const f32x4*)(n0p + lw + 192);
        c1a = *(const f32x4*)(n1p + lw);
        c1b = *(const f32x4*)(n1p + lw + 64);
        c1c = *(const f32x4*)(n1p + lw + 128);
        c1d = *(const f32x4*)(n1p + lw + 192);
      }
    }
    // stream out this depth's z (nontemporal; younger than the loads above)
    {
      float* zo = out + (size_t)ZBASE + (size_t)oi*NL;
      __builtin_nontemporal_store(zs0, (f32x4*)(zo + lw));
      __builtin_nontemporal_store(zs1, (f32x4*)(zo + lw + 64));
      __builtin_nontemporal_store(zs2, (f32x4*)(zo + lw + 128));
      __builtin_nontemporal_store(zs3, (f32x4*)(zo + lw + 192));
    }
    if (l == 0) { idxws[oi] = kc; pd[oi] = make_float2((float)d0,(float)d1); }
  }
}

// Fused mid kernel: blocks 0..31 = per-(m,d) node stats (argmin/hist/ec/ce sums)
// + coalesced idx-float writes into out[]; blocks 32.. = s-table dots.
__global__ __launch_bounds__(256) void k_mid(
    const float* __restrict__ xs, const float* __restrict__ tree,
    const float2* __restrict__ pd, const int* __restrict__ idxws,
    const float* __restrict__ nc,
    unsigned int* __restrict__ cnt, double* __restrict__ rec,
    double* __restrict__ rce, double* __restrict__ stab,
    float* __restrict__ out)
{
  __shared__ unsigned long long nmin[128*8];
  __shared__ unsigned int hc[128*8];
  __shared__ double sh[256];
  int t = threadIdx.x;
  if (blockIdx.x < 32) {
    int bid = blockIdx.x; int m = bid >> 3, d = bid & 7;
    int K = 1 << d, off = K - 1;
    for (int i = t; i < K*8; i += 256) { nmin[i] = INFPACK; hc[i] = 0u; }
    __syncthreads();
    int st = t & 7;
    double a = 0;
    if (d == 0) {
      const float2* pp = pd + (size_t)(m*NDEPTH)*NB;
      float* ob = out + (size_t)(m*NDEPTH)*NB;
      for (int b = t; b < NB; b += 256) {
        float2 v = pp[b]; a += (double)v.x;
        atomicMin(&nmin[st], packf(v.x, b));
        ob[b] = 0.0f;
      }
    } else {
      const int* pidx = idxws + (m*NDEPTH + d - 1)*NB;
      const int* cidx = idxws + (m*NDEPTH + d)*NB;
      const float2* pp = pd + (size_t)(m*NDEPTH + d)*NB;
      float* ob = out + (size_t)(m*NDEPTH + d)*NB;
      for (int b = t; b < NB; b += 256) {
        int pk = pidx[b]; float2 v = pp[b];
        int cc = cidx[b];
        a += (double)fminf(v.x, v.y);
        atomicMin(&nmin[(2*pk  )*8 + st], packf(v.x, b));
        atomicMin(&nmin[(2*pk+1)*8 + st], packf(v.y, b));
        atomicAdd(&hc[cc*8 + st], 1u);
        ob[b] = (float)cc;
      }
    }
    sh[t] = a; __syncthreads();
    for (int s = 128; s > 0; s >>= 1) { if (t < s) sh[t] += sh[t+s]; __syncthreads(); }
    if (t == 0) rec[bid] = sh[0];
    for (int i = t; i < K; i += 256) {
      unsigned long long mn = nmin[i*8];
      unsigned int c = hc[i*8];
      #pragma unroll
      for (int s = 1; s < 8; ++s) { mn = min(mn, nmin[i*8+s]); c += hc[i*8+s]; }
      nmin[i*8] = mn;
      cnt[m*NNODES + off + i] = (d == 0) ? (unsigned)NB : c;
    }
    __syncthreads();
    int wv = t >> 6, ln = t & 63;
    for (int i = wv; i < K; i += 4) {
      unsigned int b2 = (unsigned int)(nmin[i*8] & 0xFFFFFFFFULL);
      const float4* xr = (const float4*)(xs + ((size_t)m*NB + b2)*NL);
      const float4* er = (const float4*)(tree + (size_t)(m*NNODES + off + i)*(2*NL));
      float4 xv = xr[ln], ev = er[ln];
      double dx=(double)xv.x-(double)ev.x, dy=(double)xv.y-(double)ev.y;
      double dz=(double)xv.z-(double)ev.z, dw=(double)xv.w-(double)ev.w;
      double s = wred(dx*dx + dy*dy + dz*dz + dw*dw);
      if (ln == 0) sh[i] = s;
    }
    __syncthreads();
    double c2 = (t < K) ? sh[t] : 0.0;
    __syncthreads();
    sh[t] = c2; __syncthreads();
    for (int s = 128; s > 0; s >>= 1) { if (t < s) sh[t] += sh[t+s]; __syncthreads(); }
    if (t == 0) rce[bid] = sh[0];
  } else {
    // s-table: one wave per (pair,d,i,j), grid-stride
    int wid0 = (int)((blockIdx.x - 32)*4 + (t >> 6));
    int lane = t & 63;
    int nw = (int)(gridDim.x - 32)*4;
    for (int w = wid0; w < 3*STAB_PP; w += nw) {
      int p = w / STAB_PP, r = w - p*STAB_PP;
      int d = 0;
      while (d < 7 && r >= c_pref[d+1]) ++d;
      int q = r - c_pref[d]; int K = 1 << d; int off = K - 1;
      int i = q >> d, j = q & (K - 1);
      float4 av = ((const float4*)(nc + (size_t)(p*NNODES + off + i)*NL))[lane];
      float4 bv = ((const float4*)(nc + (size_t)((p+1)*NNODES + off + j)*NL))[lane];
      double s = wred(dot4d(av, bv));
      if (lane == 0) stab[w] = s / 0.07;
    }
  }
}

// Fused tail: blocks 0..23 = nce (LSE + per-b sum), blocks 24..47 = wasserstein.
__global__ __launch_bounds__(256) void k_tail(const double* __restrict__ stab,
    const unsigned int* __restrict__ cnt, const int* __restrict__ idxws,
    double* __restrict__ rnc, double* __restrict__ rw) {
  int t = threadIdx.x;
  if (blockIdx.x < 24) {
    int bid = blockIdx.x; int d = bid / 3, p = bid % 3;
    int K = 1 << d, off = K - 1;
    __shared__ unsigned int cnl[128];
    __shared__ double lsel[128];
    __shared__ double sh[256];
    if (t < K) cnl[t] = cnt[(p+1)*NNODES + off + t];
    __syncthreads();
    const double* sb = stab + (size_t)p*STAB_PP + c_pref[d];
    if (t < K) {
      const double* srow = sb + (size_t)t*K;
      double mx = -1e300;
      for (int j = 0; j < K; ++j) if (cnl[j] > 0u) { double v = srow[j]; if (v > mx) mx = v; }
      double s = 0;
      for (int j = 0; j < K; ++j) if (cnl[j] > 0u) s += (double)cnl[j]*exp(srow[j] - mx);
      lsel[t] = mx + log(s);
    }
    __syncthreads();
    const int* im  = idxws + (p*NDEPTH + d)*NB;
    const int* in_ = idxws + ((p+1)*NDEPTH + d)*NB;
    double a = 0;
    for (int b = t; b < NB; b += 256) {
      int cm = im[b], cn2 = in_[b];
      a += sb[(size_t)cm*K + cn2] - lsel[cm];
    }
    sh[t] = a; __syncthreads();
    for (int s = 128; s > 0; s >>= 1) { if (t < s) sh[t] += sh[t+s]; __syncthreads(); }
    if (t == 0) rnc[bid] = sh[0];
  } else {
    int bid = blockIdx.x - 24; int d = bid / 3, p = bid % 3;
    int K = 1 << d, off = K - 1;
    __shared__ double A[128], Bv[128], Rd[128];
    __shared__ double Wsh;
    if (t < 128) {
      A[t]  = (t < K) ? (double)cnt[p*NNODES + off + t]     : 0.0;
      Bv[t] = (t < K) ? (double)cnt[(p+1)*NNODES + off + t] : 0.0;
    }
    if (t == 0) Wsh = 0.0;
    __syncthreads();
    if (t < 128) Rd[t] = A[t];
    __syncthreads();
    for (int s = 64; s > 0; s >>= 1) { if (t < s) Rd[t] += Rd[t+s]; __syncthreads(); }
    double s1 = Rd[0];
    __syncthreads();
    if (t < 128) Rd[t] = Bv[t];
    __syncthreads();
    for (int s = 64; s > 0; s >>= 1) { if (t < s) Rd[t] += Rd[t+s]; __syncthreads(); }
    double s2 = Rd[0];
    __syncthreads();
    double i1 = 1.0/(s1 + 1e-8), i2 = 1.0/(s2 + 1e-8);
    if (t < K) { A[t] *= i1; Bv[t] *= i2; }
    __syncthreads();
    for (int n = K; n > 1; n >>= 1) {
      if (t < 128) Rd[t] = (t < n) ? fabs(A[t] - Bv[t]) : 0.0;
      __syncthreads();
      for (int s = 64; s > 0; s >>= 1) { if (t < s) Rd[t] += Rd[t+s]; __syncthreads(); }
      if (t == 0) Wsh += Rd[0];
      int h = n >> 1;
      double na = 0, nb = 0;
      if (t < h) { na = A[2*t] + A[2*t+1]; nb = Bv[2*t] + Bv[2*t+1]; }
      __syncthreads();
      if (t < h) { A[t] = na; Bv[t] = nb; }
      __syncthreads();
    }
    if (t == 0) rw[bid] = Wsh;
  }
}

// final scalar assembly
__global__ __launch_bounds__(256) void k_final(const double* __restrict__ klp,
    const double* __restrict__ rec, const double* __restrict__ rce,
    const double* __restrict__ rnc, const double* __restrict__ rw,
    float* __restrict__ out) {
  __shared__ double sh[256];
  int t = threadIdx.x;
  double a = 0;
  for (int i = t; i < NM*NNODES; i += 256) a += klp[i];
  sh[t] = a; __syncthreads();
  for (int s = 128; s > 0; s >>= 1) { if (t < s) sh[t] += sh[t+s]; __syncthreads(); }
  if (t == 0) {
    double kl = 0.5*sh[0] / ((double)NM*NNODES*NL);
    double vq = 0;
    for (int m = 0; m < NM; ++m)
      for (int d = 0; d < NDEPTH; ++d) {
        double K = (double)(1 << d);
        vq += 2.0*rec[m*NDEPTH + d]/((double)NB*NL)
            + 2.0*rce[m*NDEPTH + d]/(K*(double)NL);
      }
    double align = 0;
    for (int d = 0; d < NDEPTH; ++d)
      for (int p = 0; p < 3; ++p)
        align += rw[d*3 + p] - rnc[d*3 + p]/(double)NB;
    out[TOTAL_IDX] = (float)(vq + kl + align);
  }
}

extern "C" void kernel_launch(void* const* d_in, const int* in_sizes, int n_in,
                              void* d_out, int out_size, void* d_ws, size_t ws_size,
                              hipStream_t stream) {
  (void)in_sizes; (void)n_in; (void)out_size; (void)ws_size;
  const float* xs   = (const float*)d_in[0];   // (4, 8192, 256) f32
  const float* tree = (const float*)d_in[1];   // (4, 255, 512) f32
  float* out = (float*)d_out;
  char* ws = (char*)d_ws;

  double* en   = (double*)(ws + OFF_EN);
  double* klp  = (double*)(ws + OFF_KLP);
  float2* pd   = (float2*)(ws + OFF_PD);
  double* stab = (double*)(ws + OFF_STAB);
  double* rec  = (double*)(ws + OFF_REC);
  double* rce  = (double*)(ws + OFF_RCE);
  double* rnc  = (double*)(ws + OFF_RNC);
  double* rw   = (double*)(ws + OFF_RW);
  unsigned int* cnt = (unsigned int*)(ws + OFF_CNT);
  int* idxws   = (int*)(ws + OFF_IDX);
  float* nc    = (float*)(ws + OFF_NC);

  k_prep   <<<255, 256, 0, stream>>>(tree, en, klp, nc);
  k_decide <<<2048, 256, 0, stream>>>(xs, tree, en, out, idxws, pd);
  k_mid    <<<2048, 256, 0, stream>>>(xs, tree, pd, idxws, nc, cnt, rec, rce, stab, out);
  k_tail   <<<48, 256, 0, stream>>>(stab, cnt, idxws, rnc, rw);
  k_final  <<<1, 256, 0, stream>>>(klp, rec, rce, rnc, rw, out);
}

// Round 14
// 165.603 us; speedup vs baseline: 1.5015x; 1.0060x over previous
//
#include <hip/hip_runtime.h>

// Problem constants (match reference)
#define NM     4
#define NDEPTH 8
#define NL     256
#define NB     8192
#define NNODES 255            // 2^8 - 1
#define STAB_PP 21845         // sum_{d<8} 4^d
#define ZBASE  (NM*NDEPTH*NB)                 // 262144 (idx region size)
#define TOTAL_IDX (ZBASE + (size_t)NM*NDEPTH*NB*NL)  // 67371008
#define INFPACK (0x7F800000ULL << 32)
#define NROWS (NM*NDEPTH*NB)  // 262144
#define CACHED_NODES 31       // depths 0..4 in LDS
#define NODE_W 292            // words per cached node (256 + 36 pad -> bank spread)

typedef float f32x4 __attribute__((ext_vector_type(4)));

__device__ __constant__ int c_pref[8] = {0,1,5,21,85,341,1365,5461}; // (4^d-1)/3

// ---------- helpers ----------
__device__ __forceinline__ double wred(double v) {
  v += __shfl_xor(v, 1, 64);
  v += __shfl_xor(v, 2, 64);
  v += __shfl_xor(v, 4, 64);
  v += __shfl_xor(v, 8, 64);
  v += __shfl_xor(v, 16, 64);
  v += __shfl_xor(v, 32, 64);
  return v;
}
__device__ __forceinline__ void wred2(double& a, double& b) {
  #pragma unroll
  for (int m = 1; m <= 32; m <<= 1) {
    double ta = __shfl_xor(a, m, 64);
    double tb = __shfl_xor(b, m, 64);
    a += ta; b += tb;
  }
}
// width-16 dual reduction (serves 4 rows per wave): 4 levels
__device__ __forceinline__ void wred2_16(double& a, double& b) {
  #pragma unroll
  for (int m = 1; m <= 8; m <<= 1) {
    double ta = __shfl_xor(a, m, 16);
    double tb = __shfl_xor(b, m, 16);
    a += ta; b += tb;
  }
}
__device__ __forceinline__ double dot4d(const float4 a, const float4 b) {
  return (double)a.x*(double)b.x + (double)a.y*(double)b.y
       + (double)a.z*(double)b.z + (double)a.w*(double)b.w;
}
// balanced-tree dot of 16 pre-converted f64 x elems against 4 f32x4 chunks:
// 8 independent mul+fma pairs, then 3 add levels — dependency depth ~5 vs 16.
__device__ __forceinline__ double dot16dx(const double* xd,
    const f32x4 a, const f32x4 b, const f32x4 c, const f32x4 d) {
  double s0 = xd[0]*(double)a.x + xd[1]*(double)a.y;
  double s1 = xd[2]*(double)a.z + xd[3]*(double)a.w;
  double s2 = xd[4]*(double)b.x + xd[5]*(double)b.y;
  double s3 = xd[6]*(double)b.z + xd[7]*(double)b.w;
  double s4 = xd[8]*(double)c.x + xd[9]*(double)c.y;
  double s5 = xd[10]*(double)c.z + xd[11]*(double)c.w;
  double s6 = xd[12]*(double)d.x + xd[13]*(double)d.y;
  double s7 = xd[14]*(double)d.z + xd[15]*(double)d.w;
  return ((s0 + s1) + (s2 + s3)) + ((s4 + s5) + (s6 + s7));
}
__device__ __forceinline__ unsigned long long packf(float dist, int b) {
  // dist is always positive here -> f32 bit pattern is order-preserving.
  return ((unsigned long long)__float_as_uint(dist) << 32) | (unsigned int)b;
}

// ---------- ws layout (bytes, all 8B aligned) ----------
static constexpr size_t OFF_EN   = 0;                          // 1020 double
static constexpr size_t OFF_KLP  = OFF_EN   + 1020*8;          // 1020 double
static constexpr size_t OFF_PD   = OFF_KLP  + 1020*8;          // 262144 float2
static constexpr size_t OFF_STAB = OFF_PD   + (size_t)262144*8;// 65535 double
static constexpr size_t OFF_REC  = OFF_STAB + (size_t)65535*8; // 32 double
static constexpr size_t OFF_RCE  = OFF_REC  + 32*8;            // 32 double
static constexpr size_t OFF_RNC  = OFF_RCE  + 32*8;            // 24 double
static constexpr size_t OFF_RW   = OFF_RNC  + 24*8;            // 24 double
static constexpr size_t OFF_CNT  = OFF_RW   + 24*8;            // 1020 u32
static constexpr size_t OFF_IDX  = OFF_CNT  + 1020*4;          // 262144 int
static constexpr size_t OFF_NC   = OFF_IDX  + (size_t)262144*4;// 261120 float

// ---------- kernels ----------

// one wave per (m,node): node norms, kl partials, normalized codewords
__global__ __launch_bounds__(256) void k_prep(const float* __restrict__ tree,
    double* __restrict__ en, double* __restrict__ klp, float* __restrict__ nc) {
  int w = (int)((blockIdx.x*blockDim.x + threadIdx.x) >> 6);
  int lane = threadIdx.x & 63;
  if (w >= NM*NNODES) return;
  const float* row = tree + (size_t)w*(2*NL);
  float4 mu = ((const float4*)row)[lane];
  float4 lv = ((const float4*)(row + NL))[lane];
  double s2 = dot4d(mu, mu);
  double kp = exp((double)lv.x)+exp((double)lv.y)+exp((double)lv.z)+exp((double)lv.w)
            - (double)lv.x-(double)lv.y-(double)lv.z-(double)lv.w + s2 - 4.0;
  double s2t = s2, kpt = kp;
  wred2(s2t, kpt);
  double inv = 1.0 / fmax(sqrt(s2t), 1e-12);
  float4 o;
  o.x=(float)(mu.x*inv); o.y=(float)(mu.y*inv); o.z=(float)(mu.z*inv); o.w=(float)(mu.w*inv);
  ((float4*)(nc + (size_t)w*NL))[lane] = o;
  if (lane == 0) { en[w] = s2t; klp[w] = kpt; }
}

// 16 lanes per row, 4 rows per wave, 16 rows per 256-thread block (R13 structure).
// Single-variable A/B vs R13: z-stores are PLAIN stores (write-back via L2),
// not nontemporal — isolating the nt-store path's contribution.
__global__ __launch_bounds__(256) void k_decide(
    const float* __restrict__ xs, const float* __restrict__ tree,
    const double* __restrict__ en, float* __restrict__ out,
    int* __restrict__ idxws, float2* __restrict__ pd)
{
  __shared__ float s_tree[CACHED_NODES * NODE_W];   // 36,208 B
  __shared__ double s_en[NNODES];                   //  2,040 B
  int t = threadIdx.x;
  int blk = blockIdx.x;
  int m = (int)(((unsigned)blk * 16) >> 13);
  const float* treem = tree + (size_t)m*NNODES*(2*NL);
  for (int j = t; j < CACHED_NODES*64; j += 256) {
    int node = j >> 6, w4 = j & 63;
    *(f32x4*)&s_tree[node*NODE_W + w4*4] =
        *(const f32x4*)(treem + (size_t)node*(2*NL) + w4*4);
  }
  if (t < NNODES) s_en[t] = en[m*NNODES + t];
  __syncthreads();

  int wv = t >> 6, lane = t & 63;
  int g = lane >> 4, l = lane & 15;
  int row = blk*16 + wv*4 + g;
  int b = row & (NB-1);
  int lw = l*4;                       // word offset of this lane's first chunk

  // x: 4 f32x4 chunks at words lw + k*64 (nontemporal loads)
  const float* xrow = xs + (size_t)row*NL;
  f32x4 x0 = __builtin_nontemporal_load((const f32x4*)(xrow + lw));
  f32x4 x1 = __builtin_nontemporal_load((const f32x4*)(xrow + lw + 64));
  f32x4 x2 = __builtin_nontemporal_load((const f32x4*)(xrow + lw + 128));
  f32x4 x3 = __builtin_nontemporal_load((const f32x4*)(xrow + lw + 192));
  double xd[16];
  xd[0]=(double)x0.x; xd[1]=(double)x0.y; xd[2]=(double)x0.z; xd[3]=(double)x0.w;
  xd[4]=(double)x1.x; xd[5]=(double)x1.y; xd[6]=(double)x1.z; xd[7]=(double)x1.w;
  xd[8]=(double)x2.x; xd[9]=(double)x2.y; xd[10]=(double)x2.z; xd[11]=(double)x2.w;
  xd[12]=(double)x3.x; xd[13]=(double)x3.y; xd[14]=(double)x3.z; xd[15]=(double)x3.w;

  // depth 0: node 0 from LDS
  f32x4 e0 = *(const f32x4*)&s_tree[lw];
  f32x4 e1 = *(const f32x4*)&s_tree[lw + 64];
  f32x4 e2 = *(const f32x4*)&s_tree[lw + 128];
  f32x4 e3 = *(const f32x4*)&s_tree[lw + 192];
  // balanced-tree xn
  double xn;
  {
    double n0 = xd[0]*xd[0] + xd[1]*xd[1];
    double n1 = xd[2]*xd[2] + xd[3]*xd[3];
    double n2 = xd[4]*xd[4] + xd[5]*xd[5];
    double n3 = xd[6]*xd[6] + xd[7]*xd[7];
    double n4 = xd[8]*xd[8] + xd[9]*xd[9];
    double n5 = xd[10]*xd[10] + xd[11]*xd[11];
    double n6 = xd[12]*xd[12] + xd[13]*xd[13];
    double n7 = xd[14]*xd[14] + xd[15]*xd[15];
    xn = ((n0 + n1) + (n2 + n3)) + ((n4 + n5) + (n6 + n7));
  }
  double rr = dot16dx(xd, e0, e1, e2, e3);
  wred2_16(xn, rr);
  double dd0 = xn + s_en[0] - 2.0*rr;
  int oi = (m*NDEPTH)*NB + b;
  if (l == 0) { idxws[oi] = 0; pd[oi] = make_float2((float)dd0,(float)dd0); }

  // load depth-1 candidates (nodes 1,2) from LDS
  f32x4 c0a = *(const f32x4*)&s_tree[1*NODE_W + lw];
  f32x4 c0b = *(const f32x4*)&s_tree[1*NODE_W + lw + 64];
  f32x4 c0c = *(const f32x4*)&s_tree[1*NODE_W + lw + 128];
  f32x4 c0d = *(const f32x4*)&s_tree[1*NODE_W + lw + 192];
  f32x4 c1a = *(const f32x4*)&s_tree[2*NODE_W + lw];
  f32x4 c1b = *(const f32x4*)&s_tree[2*NODE_W + lw + 64];
  f32x4 c1c = *(const f32x4*)&s_tree[2*NODE_W + lw + 128];
  f32x4 c1d = *(const f32x4*)&s_tree[2*NODE_W + lw + 192];

  // store z of depth 0 (node 0) — plain stores
  {
    float* zo = out + (size_t)ZBASE + (size_t)oi*NL;
    *(f32x4*)(zo + lw)       = e0;
    *(f32x4*)(zo + lw + 64)  = e1;
    *(f32x4*)(zo + lw + 128) = e2;
    *(f32x4*)(zo + lw + 192) = e3;
  }

  int pk = 0;
  #pragma unroll
  for (int d = 1; d < NDEPTH; ++d) {
    int n0 = (1 << d) - 1 + 2*pk;
    double r0 = dot16dx(xd, c0a, c0b, c0c, c0d);
    double r1 = dot16dx(xd, c1a, c1b, c1c, c1d);
    wred2_16(r0, r1);
    double en0 = s_en[n0], en1 = s_en[n0+1];
    double d0 = xn + en0 - 2.0*r0;
    double d1 = xn + en1 - 2.0*r1;
    bool p1s = (d1 < d0);                 // tie -> even child, matches argmin
    int kc = 2*pk + (p1s ? 1 : 0);
    // copy selected codeword out of the candidate regs before they are reloaded
    f32x4 zs0 = p1s ? c1a : c0a;
    f32x4 zs1 = p1s ? c1b : c0b;
    f32x4 zs2 = p1s ? c1c : c0c;
    f32x4 zs3 = p1s ? c1d : c0d;
    oi = (m*NDEPTH + d)*NB + b;
    pk = kc;
    // issue next depth's candidate loads BEFORE this depth's z-stores
    if (d < NDEPTH-1) {
      int nn = (1 << (d+1)) - 1 + 2*pk;
      if (d + 1 <= 4) {
        c0a = *(const f32x4*)&s_tree[nn*NODE_W + lw];
        c0b = *(const f32x4*)&s_tree[nn*NODE_W + lw + 64];
        c0c = *(const f32x4*)&s_tree[nn*NODE_W + lw + 128];
        c0d = *(const f32x4*)&s_tree[nn*NODE_W + lw + 192];
        c1a = *(const f32x4*)&s_tree[(nn+1)*NODE_W + lw];
        c1b = *(const f32x4*)&s_tree[(nn+1)*NODE_W + lw + 64];
        c1c = *(const f32x4*)&s_tree[(nn+1)*NODE_W + lw + 128];
        c1d = *(const f32x4*)&s_tree[(nn+1)*NODE_W + lw + 192];
      } else {
        const float* n0p = treem + (size_t)nn*(2*NL);
        const float* n1p = n0p + 2*NL;
        c0a = *(const f32x4*)(n0p + lw);
        c0b = *(const f32x4*)(n0p + lw + 64);
        c0c = *(const f32x4*)(n0p + lw + 128);
        c0d = *(const f32x4*)(n0p + lw + 192);
        c1a = *(const f32x4*)(n1p + lw);
        c1b = *(const f32x4*)(n1p + lw + 64);
        c1c = *(const f32x4*)(n1p + lw + 128);
        c1d = *(const f32x4*)(n1p + lw + 192);
      }
    }
    // stream out this depth's z (plain stores; younger than the loads above)
    {
      float* zo = out + (size_t)ZBASE + (size_t)oi*NL;
      *(f32x4*)(zo + lw)       = zs0;
      *(f32x4*)(zo + lw + 64)  = zs1;
      *(f32x4*)(zo + lw + 128) = zs2;
      *(f32x4*)(zo + lw + 192) = zs3;
    }
    if (l == 0) { idxws[oi] = kc; pd[oi] = make_float2((float)d0,(float)d1); }
  }
}

// Fused mid kernel: blocks 0..31 = per-(m,d) node stats (argmin/hist/ec/ce sums)
// + coalesced idx-float writes into out[]; blocks 32.. = s-table dots.
__global__ __launch_bounds__(256) void k_mid(
    const float* __restrict__ xs, const float* __restrict__ tree,
    const float2* __restrict__ pd, const int* __restrict__ idxws,
    const float* __restrict__ nc,
    unsigned int* __restrict__ cnt, double* __restrict__ rec,
    double* __restrict__ rce, double* __restrict__ stab,
    float* __restrict__ out)
{
  __shared__ unsigned long long nmin[128*8];
  __shared__ unsigned int hc[128*8];
  __shared__ double sh[256];
  int t = threadIdx.x;
  if (blockIdx.x < 32) {
    int bid = blockIdx.x; int m = bid >> 3, d = bid & 7;
    int K = 1 << d, off = K - 1;
    for (int i = t; i < K*8; i += 256) { nmin[i] = INFPACK; hc[i] = 0u; }
    __syncthreads();
    int st = t & 7;
    double a = 0;
    if (d == 0) {
      const float2* pp = pd + (size_t)(m*NDEPTH)*NB;
      float* ob = out + (size_t)(m*NDEPTH)*NB;
      for (int b = t; b < NB; b += 256) {
        float2 v = pp[b]; a += (double)v.x;
        atomicMin(&nmin[st], packf(v.x, b));
        ob[b] = 0.0f;
      }
    } else {
      const int* pidx = idxws + (m*NDEPTH + d - 1)*NB;
      const int* cidx = idxws + (m*NDEPTH + d)*NB;
      const float2* pp = pd + (size_t)(m*NDEPTH + d)*NB;
      float* ob = out + (size_t)(m*NDEPTH + d)*NB;
      for (int b = t; b < NB; b += 256) {
        int pk = pidx[b]; float2 v = pp[b];
        int cc = cidx[b];
        a += (double)fminf(v.x, v.y);
        atomicMin(&nmin[(2*pk  )*8 + st], packf(v.x, b));
        atomicMin(&nmin[(2*pk+1)*8 + st], packf(v.y, b));
        atomicAdd(&hc[cc*8 + st], 1u);
        ob[b] = (float)cc;
      }
    }
    sh[t] = a; __syncthreads();
    for (int s = 128; s > 0; s >>= 1) { if (t < s) sh[t] += sh[t+s]; __syncthreads(); }
    if (t == 0) rec[bid] = sh[0];
    for (int i = t; i < K; i += 256) {
      unsigned long long mn = nmin[i*8];
      unsigned int c = hc[i*8];
      #pragma unroll
      for (int s = 1; s < 8; ++s) { mn = min(mn, nmin[i*8+s]); c += hc[i*8+s]; }
      nmin[i*8] = mn;
      cnt[m*NNODES + off + i] = (d == 0) ? (unsigned)NB : c;
    }
    __syncthreads();
    int wv = t >> 6, ln = t & 63;
    for (int i = wv; i < K; i += 4) {
      unsigned int b2 = (unsigned int)(nmin[i*8] & 0xFFFFFFFFULL);
      const float4* xr = (const float4*)(xs + ((size_t)m*NB + b2)*NL);
      const float4* er = (const float4*)(tree + (size_t)(m*NNODES + off + i)*(2*NL));
      float4 xv = xr[ln], ev = er[ln];
      double dx=(double)xv.x-(double)ev.x, dy=(double)xv.y-(double)ev.y;
      double dz=(double)xv.z-(double)ev.z, dw=(double)xv.w-(double)ev.w;
      double s = wred(dx*dx + dy*dy + dz*dz + dw*dw);
      if (ln == 0) sh[i] = s;
    }
    __syncthreads();
    double c2 = (t < K) ? sh[t] : 0.0;
    __syncthreads();
    sh[t] = c2; __syncthreads();
    for (int s = 128; s > 0; s >>= 1) { if (t < s) sh[t] += sh[t+s]; __syncthreads(); }
    if (t == 0) rce[bid] = sh[0];
  } else {
    // s-table: one wave per (pair,d,i,j), grid-stride
    int wid0 = (int)((blockIdx.x - 32)*4 + (t >> 6));
    int lane = t & 63;
    int nw = (int)(gridDim.x - 32)*4;
    for (int w = wid0; w < 3*STAB_PP; w += nw) {
      int p = w / STAB_PP, r = w - p*STAB_PP;
      int d = 0;
      while (d < 7 && r >= c_pref[d+1]) ++d;
      int q = r - c_pref[d]; int K = 1 << d; int off = K - 1;
      int i = q >> d, j = q & (K - 1);
      float4 av = ((const float4*)(nc + (size_t)(p*NNODES + off + i)*NL))[lane];
      float4 bv = ((const float4*)(nc + (size_t)((p+1)*NNODES + off + j)*NL))[lane];
      double s = wred(dot4d(av, bv));
      if (lane == 0) stab[w] = s / 0.07;
    }
  }
}

// Fused tail: blocks 0..23 = nce (LSE + per-b sum), blocks 24..47 = wasserstein.
__global__ __launch_bounds__(256) void k_tail(const double* __restrict__ stab,
    const unsigned int* __restrict__ cnt, const int* __restrict__ idxws,
    double* __restrict__ rnc, double* __restrict__ rw) {
  int t = threadIdx.x;
  if (blockIdx.x < 24) {
    int bid = blockIdx.x; int d = bid / 3, p = bid % 3;
    int K = 1 << d, off = K - 1;
    __shared__ unsigned int cnl[128];
    __shared__ double lsel[128];
    __shared__ double sh[256];
    if (t < K) cnl[t] = cnt[(p+1)*NNODES + off + t];
    __syncthreads();
    const double* sb = stab + (size_t)p*STAB_PP + c_pref[d];
    if (t < K) {
      const double* srow = sb + (size_t)t*K;
      double mx = -1e300;
      for (int j = 0; j < K; ++j) if (cnl[j] > 0u) { double v = srow[j]; if (v > mx) mx = v; }
      double s = 0;
      for (int j = 0; j < K; ++j) if (cnl[j] > 0u) s += (double)cnl[j]*exp(srow[j] - mx);
      lsel[t] = mx + log(s);
    }
    __syncthreads();
    const int* im  = idxws + (p*NDEPTH + d)*NB;
    const int* in_ = idxws + ((p+1)*NDEPTH + d)*NB;
    double a = 0;
    for (int b = t; b < NB; b += 256) {
      int cm = im[b], cn2 = in_[b];
      a += sb[(size_t)cm*K + cn2] - lsel[cm];
    }
    sh[t] = a; __syncthreads();
    for (int s = 128; s > 0; s >>= 1) { if (t < s) sh[t] += sh[t+s]; __syncthreads(); }
    if (t == 0) rnc[bid] = sh[0];
  } else {
    int bid = blockIdx.x - 24; int d = bid / 3, p = bid % 3;
    int K = 1 << d, off = K - 1;
    __shared__ double A[128], Bv[128], Rd[128];
    __shared__ double Wsh;
    if (t < 128) {
      A[t]  = (t < K) ? (double)cnt[p*NNODES + off + t]     : 0.0;
      Bv[t] = (t < K) ? (double)cnt[(p+1)*NNODES + off + t] : 0.0;
    }
    if (t == 0) Wsh = 0.0;
    __syncthreads();
    if (t < 128) Rd[t] = A[t];
    __syncthreads();
    for (int s = 64; s > 0; s >>= 1) { if (t < s) Rd[t] += Rd[t+s]; __syncthreads(); }
    double s1 = Rd[0];
    __syncthreads();
    if (t < 128) Rd[t] = Bv[t];
    __syncthreads();
    for (int s = 64; s > 0; s >>= 1) { if (t < s) Rd[t] += Rd[t+s]; __syncthreads(); }
    double s2 = Rd[0];
    __syncthreads();
    double i1 = 1.0/(s1 + 1e-8), i2 = 1.0/(s2 + 1e-8);
    if (t < K) { A[t] *= i1; Bv[t] *= i2; }
    __syncthreads();
    for (int n = K; n > 1; n >>= 1) {
      if (t < 128) Rd[t] = (t < n) ? fabs(A[t] - Bv[t]) : 0.0;
      __syncthreads();
      for (int s = 64; s > 0; s >>= 1) { if (t < s) Rd[t] += Rd[t+s]; __syncthreads(); }
      if (t == 0) Wsh += Rd[0];
      int h = n >> 1;
      double na = 0, nb = 0;
      if (t < h) { na = A[2*t] + A[2*t+1]; nb = Bv[2*t] + Bv[2*t+1]; }
      __syncthreads();
      if (t < h) { A[t] = na; Bv[t] = nb; }
      __syncthreads();
    }
    if (t == 0) rw[bid] = Wsh;
  }
}

// final scalar assembly
__global__ __launch_bounds__(256) void k_final(const double* __restrict__ klp,
    const double* __restrict__ rec, const double* __restrict__ rce,
    const double* __restrict__ rnc, const double* __restrict__ rw,
    float* __restrict__ out) {
  __shared__ double sh[256];
  int t = threadIdx.x;
  double a = 0;
  for (int i = t; i < NM*NNODES; i += 256) a += klp[i];
  sh[t] = a; __syncthreads();
  for (int s = 128; s > 0; s >>= 1) { if (t < s) sh[t] += sh[t+s]; __syncthreads(); }
  if (t == 0) {
    double kl = 0.5*sh[0] / ((double)NM*NNODES*NL);
    double vq = 0;
    for (int m = 0; m < NM; ++m)
      for (int d = 0; d < NDEPTH; ++d) {
        double K = (double)(1 << d);
        vq += 2.0*rec[m*NDEPTH + d]/((double)NB*NL)
            + 2.0*rce[m*NDEPTH + d]/(K*(double)NL);
      }
    double align = 0;
    for (int d = 0; d < NDEPTH; ++d)
      for (int p = 0; p < 3; ++p)
        align += rw[d*3 + p] - rnc[d*3 + p]/(double)NB;
    out[TOTAL_IDX] = (float)(vq + kl + align);
  }
}

extern "C" void kernel_launch(void* const* d_in, const int* in_sizes, int n_in,
                              void* d_out, int out_size, void* d_ws, size_t ws_size,
                              hipStream_t stream) {
  (void)in_sizes; (void)n_in; (void)out_size; (void)ws_size;
  const float* xs   = (const float*)d_in[0];   // (4, 8192, 256) f32
  const float* tree = (const float*)d_in[1];   // (4, 255, 512) f32
  float* out = (float*)d_out;
  char* ws = (char*)d_ws;

  double* en   = (double*)(ws + OFF_EN);
  double* klp  = (double*)(ws + OFF_KLP);
  float2* pd   = (float2*)(ws + OFF_PD);
  double* stab = (double*)(ws + OFF_STAB);
  double* rec  = (double*)(ws + OFF_REC);
  double* rce  = (double*)(ws + OFF_RCE);
  double* rnc  = (double*)(ws + OFF_RNC);
  double* rw   = (double*)(ws + OFF_RW);
  unsigned int* cnt = (unsigned int*)(ws + OFF_CNT);
  int* idxws   = (int*)(ws + OFF_IDX);
  float* nc    = (float*)(ws + OFF_NC);

  k_prep   <<<255, 256, 0, stream>>>(tree, en, klp, nc);
  k_decide <<<2048, 256, 0, stream>>>(xs, tree, en, out, idxws, pd);
  k_mid    <<<2048, 256, 0, stream>>>(xs, tree, pd, idxws, nc, cnt, rec, rce, stab, out);
  k_tail   <<<48, 256, 0, stream>>>(stab, cnt, idxws, rnc, rw);
  k_final  <<<1, 256, 0, stream>>>(klp, rec, rce, rnc, rw, out);
}